// Round 5
// baseline (1066.710 us; speedup 1.0000x reference)
//
#include <hip/hip_runtime.h>
#include <hip/hip_bf16.h>

#define N_ENT   8192
#define N_USR   16384
#define CH      64
#define N_EDGEC 1000000
#define NNZC    500000
#define TOPKC   10
#define NRELM1  8

static __device__ __forceinline__ float waveReduceSum(float v){
#pragma unroll
  for(int o=1;o<64;o<<=1) v += __shfl_xor(v,o,64);
  return v;
}
static __device__ __forceinline__ float waveReduceMax(float v){
#pragma unroll
  for(int o=1;o<64;o<<=1) v = fmaxf(v, __shfl_xor(v,o,64));
  return v;
}
static __device__ __forceinline__ int waveReduceMaxI(int v){
#pragma unroll
  for(int o=1;o<64;o<<=1){ int t=__shfl_xor(v,o,64); v = t>v? t: v; }
  return v;
}
static __device__ __forceinline__ unsigned long long u64max(unsigned long long a, unsigned long long b){
  return a>b? a: b;
}
static __device__ __forceinline__ unsigned mapf(float v){
  unsigned u = __float_as_uint(v);
  return (u & 0x80000000u) ? ~u : (u | 0x80000000u);
}

// ---------------- sorting (counting sort by segment key) ----------------
__global__ void k_hist(const int* __restrict__ keys, int n, int* __restrict__ hist){
  int i = blockIdx.x*blockDim.x + threadIdx.x;
  int stride = gridDim.x*blockDim.x;
  for(; i<n; i+=stride) atomicAdd(&hist[keys[i]], 1);
}

__global__ __launch_bounds__(1024) void k_scan(const int* __restrict__ hist,
                                               int* __restrict__ start,
                                               int* __restrict__ cursor, int n){
  __shared__ int part[1024];
  int t = threadIdx.x;
  int chunk = n/1024;
  int base = t*chunk;
  int s = 0;
  for(int i=0;i<chunk;i++) s += hist[base+i];
  part[t] = s; __syncthreads();
  for(int off=1; off<1024; off<<=1){
    int v = (t>=off) ? part[t-off] : 0;
    __syncthreads();
    part[t] += v;
    __syncthreads();
  }
  int run = (t==0) ? 0 : part[t-1];
  for(int i=0;i<chunk;i++){
    start[base+i] = run; cursor[base+i] = run;
    run += hist[base+i];
  }
  if(t==1023) start[n] = run;
}

// fused: scatter edges by head, writing packed (tail | rel<<13) at sorted position
__global__ void k_scatter_sortE(const int* __restrict__ head,
                                const int* __restrict__ tail,
                                const int* __restrict__ etype, int n,
                                int* __restrict__ cursor, int* __restrict__ trS){
  int i = blockIdx.x*blockDim.x + threadIdx.x;
  int stride = gridDim.x*blockDim.x;
  for(; i<n; i+=stride){
    int pos = atomicAdd(&cursor[head[i]], 1);
    trS[pos] = (tail[i] & 8191) | ((etype[i]-1)<<13);
  }
}

// fused: scatter interactions by row, writing col + val at sorted position
__global__ void k_scatter_sortU(const int* __restrict__ irows,
                                const int* __restrict__ icols,
                                const float* __restrict__ ivals, int n,
                                int* __restrict__ cursor,
                                int* __restrict__ icolsS, float* __restrict__ ivalsS){
  int i = blockIdx.x*blockDim.x + threadIdx.x;
  int stride = gridDim.x*blockDim.x;
  for(; i<n; i+=stride){
    int pos = atomicAdd(&cursor[irows[i]], 1);
    icolsS[pos] = icols[i];
    ivalsS[pos] = ivals[i];
  }
}

// ---------------- row normalize (cn and l2norm) ----------------
__global__ __launch_bounds__(256) void k_rownorm(const float* __restrict__ in,
                                                 float* __restrict__ out,
                                                 int rows, float eps){
  int wave = threadIdx.x>>6, lane = threadIdx.x&63;
  int r = blockIdx.x*4 + wave;
  if(r>=rows) return;
  float v = in[(size_t)r*CH+lane];
  float ss = waveReduceSum(v*v);
  float nrm = sqrtf(ss);
  out[(size_t)r*CH+lane] = v / fmaxf(nrm, eps);
}

// ---------------- sim GEMM: C = A * A^T, K=64, f32 vector ALU ----------------
__global__ __launch_bounds__(256,2) void k_gemm_nt(const float* __restrict__ A,
                                                   float* __restrict__ C){
  __shared__ float As[CH][132];
  __shared__ float Bs[CH][132];
  const int tid = threadIdx.x;
  const int bi = blockIdx.y*128, bj = blockIdx.x*128;
#pragma unroll
  for(int k=0;k<8;k++){
    int idx = tid + k*256;
    int row = idx>>4;
    int c4  = (idx&15)*4;
    float4 va = ((const float4*)(A + (size_t)(bi+row)*CH))[c4>>2];
    As[c4+0][row]=va.x; As[c4+1][row]=va.y; As[c4+2][row]=va.z; As[c4+3][row]=va.w;
    float4 vb = ((const float4*)(A + (size_t)(bj+row)*CH))[c4>>2];
    Bs[c4+0][row]=vb.x; Bs[c4+1][row]=vb.y; Bs[c4+2][row]=vb.z; Bs[c4+3][row]=vb.w;
  }
  __syncthreads();
  const int tx = tid&15, ty = tid>>4;
  float acc[8][8];
#pragma unroll
  for(int i=0;i<8;i++)
#pragma unroll
    for(int j=0;j<8;j++) acc[i][j]=0.f;
#pragma unroll 8
  for(int k=0;k<CH;k++){
    float4 a0 = *(const float4*)&As[k][ty*8];
    float4 a1 = *(const float4*)&As[k][ty*8+4];
    float4 b0 = *(const float4*)&Bs[k][tx*8];
    float4 b1 = *(const float4*)&Bs[k][tx*8+4];
    float a[8]={a0.x,a0.y,a0.z,a0.w,a1.x,a1.y,a1.z,a1.w};
    float b[8]={b0.x,b0.y,b0.z,b0.w,b1.x,b1.y,b1.z,b1.w};
#pragma unroll
    for(int i=0;i<8;i++)
#pragma unroll
      for(int j=0;j<8;j++) acc[i][j] = fmaf(a[i], b[j], acc[i][j]);
  }
#pragma unroll
  for(int i=0;i<8;i++){
    float4 o0 = {acc[i][0],acc[i][1],acc[i][2],acc[i][3]};
    float4 o1 = {acc[i][4],acc[i][5],acc[i][6],acc[i][7]};
    float* crow = C + (size_t)(bi+ty*8+i)*N_ENT + bj + tx*8;
    *(float4*)crow = o0;
    *((float4*)crow+1) = o1;
  }
}

// ---------------- per-row top-k: radix-select, one wave per row ----------------
// key = mapped_float<<32 | (0xFFFFFFFF - col): larger wins; ties -> smaller col.
#define CANDCAP 256
__global__ __launch_bounds__(64) void k_topk(const float* __restrict__ S,
                                             int* __restrict__ knn_idx,
                                             float* __restrict__ knn_val,
                                             float* __restrict__ rowsum){
  const int row = blockIdx.x;
  const int lane = threadIdx.x;
  const float4* s4 = (const float4*)(S + (size_t)row*N_ENT);

  __shared__ int hist[2048];
  __shared__ unsigned long long cand[CANDCAP];
  __shared__ int cnt;
#pragma unroll
  for(int i=lane;i<2048;i+=64) hist[i]=0;
  if(lane==0) cnt=0;
  __syncthreads();

  // pass 1: histogram of mapped>>21 (sign+exp+2mant bits)
  for(int it=0; it<N_ENT/256; ++it){
    float4 v = s4[it*64+lane];
    atomicAdd(&hist[mapf(v.x)>>21],1);
    atomicAdd(&hist[mapf(v.y)>>21],1);
    atomicAdd(&hist[mapf(v.z)>>21],1);
    atomicAdd(&hist[mapf(v.w)>>21],1);
  }
  __syncthreads();

  // find cutoff bin B: smallest bin with cum(>=B) >= TOPKC
  int base = lane*32;
  int s = 0;
#pragma unroll
  for(int j=0;j<32;j++) s += hist[base+j];
  int ss = s;                                   // inclusive suffix over lanes
#pragma unroll
  for(int off=1; off<64; off<<=1){
    int t = __shfl_down(ss, off, 64);
    if(lane+off<64) ss += t;
  }
  int above = ss - s;                           // cum of lanes > this one
  int B_local = 0;
  if(ss >= TOPKC && above < TOPKC){
    int running = above;
    for(int j=31;j>=0;--j){
      running += hist[base+j];
      if(running >= TOPKC){ B_local = base+j; break; }
    }
  }
  int B = waveReduceMaxI(B_local);
  unsigned thr = (unsigned)B << 21;

  // pass 2: collect candidates (mapped >= thr) into LDS
  for(int it=0; it<N_ENT/256; ++it){
    int vi = it*64+lane;
    float4 v = s4[vi];
    int c0 = vi*4;
    float vv[4] = {v.x,v.y,v.z,v.w};
#pragma unroll
    for(int j=0;j<4;j++){
      unsigned m = mapf(vv[j]);
      if(m >= thr){
        int pos = atomicAdd(&cnt,1);
        if(pos < CANDCAP)
          cand[pos] = ((unsigned long long)m<<32)
                    | (unsigned long long)(0xFFFFFFFFu - (unsigned)(c0+j));
      }
    }
  }
  __syncthreads();
  int n = cnt;

  if(n <= CANDCAP){
    unsigned long long c0 = (lane      < n) ? cand[lane]       : 0ull;
    unsigned long long c1 = (lane+64   < n) ? cand[lane+64]    : 0ull;
    unsigned long long c2 = (lane+128  < n) ? cand[lane+128]   : 0ull;
    unsigned long long c3 = (lane+192  < n) ? cand[lane+192]   : 0ull;
    float rs = 0.f;
    for(int sel=0; sel<TOPKC; ++sel){
      unsigned long long m = u64max(u64max(c0,c1), u64max(c2,c3));
#pragma unroll
      for(int o=1;o<64;o<<=1) m = u64max(m, __shfl_xor(m,o,64));
      if(c0==m) c0=0ull; else if(c1==m) c1=0ull;
      else if(c2==m) c2=0ull; else if(c3==m) c3=0ull;
      if(lane==0){
        unsigned mk = (unsigned)(m>>32);
        unsigned uo = (mk & 0x80000000u) ? (mk ^ 0x80000000u) : ~mk;
        float v = __uint_as_float(uo);
        int col = (int)(0xFFFFFFFFu - (unsigned)(m & 0xFFFFFFFFu));
        knn_idx[row*TOPKC+sel] = col;
        knn_val[row*TOPKC+sel] = v;
        rs += v;
      }
    }
    if(lane==0) rowsum[row] = rs;
  } else {
    // pathological fallback: exact register insertion scan (legacy path)
    unsigned long long loc[TOPKC];
#pragma unroll
    for(int i=0;i<TOPKC;i++) loc[i]=0ull;
    for(int it=0; it<N_ENT/256; ++it){
      int vi = it*64+lane;
      float4 v = s4[vi];
      int c0i = vi*4;
      float vv[4] = {v.x,v.y,v.z,v.w};
#pragma unroll
      for(int j=0;j<4;j++){
        unsigned u = mapf(vv[j]);
        unsigned long long key = ((unsigned long long)u<<32)
                               | (unsigned long long)(0xFFFFFFFFu - (unsigned)(c0i+j));
        if(key > loc[TOPKC-1]){
          unsigned long long t = key;
#pragma unroll
          for(int z=0; z<TOPKC; ++z){
            if(t > loc[z]){ unsigned long long tmp=loc[z]; loc[z]=t; t=tmp; }
          }
        }
      }
    }
    float rs = 0.f;
    for(int sel=0; sel<TOPKC; ++sel){
      unsigned long long m = loc[0];
#pragma unroll
      for(int o=1;o<64;o<<=1) m = u64max(m, __shfl_xor(m,o,64));
      if(loc[0] == m){
#pragma unroll
        for(int z=0;z<TOPKC-1;++z) loc[z]=loc[z+1];
        loc[TOPKC-1]=0ull;
      }
      if(lane==0){
        unsigned mk = (unsigned)(m>>32);
        unsigned uo = (mk & 0x80000000u) ? (mk ^ 0x80000000u) : ~mk;
        float v = __uint_as_float(uo);
        int col = (int)(0xFFFFFFFFu - (unsigned)(m & 0xFFFFFFFFu));
        knn_idx[row*TOPKC+sel] = col;
        knn_val[row*TOPKC+sel] = v;
        rs += v;
      }
    }
    if(lane==0) rowsum[row] = rs;
  }
}

// ---------------- q[i][r] = ||ent_i * W_r||^2 ----------------
__global__ __launch_bounds__(256) void k_q(const float* __restrict__ ent,
                                           const float* __restrict__ W,
                                           float* __restrict__ q){
  int wave=threadIdx.x>>6, lane=threadIdx.x&63;
  int r = blockIdx.x*4+wave;
  if(r>=N_ENT) return;
  float x = ent[(size_t)r*CH+lane];
#pragma unroll
  for(int rel=0; rel<NRELM1; rel++){
    float tt = x*W[rel*CH+lane];
    float s = waveReduceSum(tt*tt);
    if(lane==0) q[r*NRELM1+rel]=s;
  }
}

// ---------------- per-head edge aggregation (contiguous sorted arrays) ----------------
__global__ __launch_bounds__(256) void k_edge_agg(
    const int* __restrict__ trS, const int* __restrict__ startE,
    const float* __restrict__ ent, const float* __restrict__ W,
    const float* __restrict__ q, float* __restrict__ wbuf,
    float* __restrict__ agg){
  int wave=threadIdx.x>>6, lane=threadIdx.x&63;
  int h = blockIdx.x*4+wave;
  if(h>=N_ENT) return;
  int s = startE[h], e2 = startE[h+1];

  float qh[NRELM1];
#pragma unroll
  for(int r=0;r<NRELM1;r++) qh[r] = q[h*NRELM1+r];

  float mx = 0.f;
  for(int p=s+lane; p<e2; p+=64){
    int tr = trS[p];
    int tl = tr & 8191, r = tr>>13;
    float att = qh[r]*q[tl*NRELM1+r];
    wbuf[p] = att;
    mx = fmaxf(mx, att);
  }
  mx = waveReduceMax(mx);

  float dn = 0.f;
  for(int p=s+lane; p<e2; p+=64){
    float e = expf(wbuf[p]-mx);
    wbuf[p] = e;
    dn += e;
  }
  dn = waveReduceSum(dn);
  float inv = (dn>0.f) ? 1.f/dn : 0.f;

  float wr[NRELM1];
#pragma unroll
  for(int r=0;r<NRELM1;r++) wr[r] = W[r*CH+lane];
  float acc = 0.f;
  for(int p=s; p<e2; p++){
    int tr = trS[p];
    int tl = tr & 8191, r = tr>>13;
    float wgt = wbuf[p]*inv;
    acc = fmaf(wgt*wr[r], ent[(size_t)tl*CH+lane], acc);
  }
  agg[(size_t)h*CH+lane] = acc;
}

// ---------------- per-user: sparse agg + gated score + l2norm + residual ----------------
__global__ __launch_bounds__(256) void k_user(
    const int* __restrict__ icolsS, const float* __restrict__ ivalsS,
    const int* __restrict__ startU,
    const float* __restrict__ ent, const float* __restrict__ W,
    float* __restrict__ usr, float* __restrict__ usr_res){
  int wave=threadIdx.x>>6, lane=threadIdx.x&63;
  int u = blockIdx.x*4+wave;
  if(u>=N_USR) return;
  float ue = usr[(size_t)u*CH+lane];
  float l[NRELM1];
#pragma unroll
  for(int r=0;r<NRELM1;r++) l[r] = waveReduceSum(ue*W[r*CH+lane]);
  float lm = l[0];
#pragma unroll
  for(int r=1;r<NRELM1;r++) lm = fmaxf(lm,l[r]);
  float se=0.f;
#pragma unroll
  for(int r=0;r<NRELM1;r++){ l[r]=expf(l[r]-lm); se+=l[r]; }
  float inv = 1.f/se;
  float g = 0.f;
#pragma unroll
  for(int r=0;r<NRELM1;r++) g = fmaf(l[r]*inv, W[r*CH+lane], g);
  float acc=0.f;
  int s=startU[u], e2=startU[u+1];
  for(int p=s;p<e2;p++){
    acc = fmaf(ivalsS[p], ent[(size_t)icolsS[p]*CH+lane], acc);
  }
  float res = acc*(1.f+g);
  float nrm = sqrtf(waveReduceSum(res*res));
  float outv = res / fmaxf(nrm, 1e-12f);
  usr_res[(size_t)u*CH+lane] += outv;
  usr[(size_t)u*CH+lane] = outv;
}

// ---------------- entity finalize: l2norm + residual ----------------
__global__ __launch_bounds__(256) void k_entfin(const float* __restrict__ agg,
                                                float* __restrict__ cur,
                                                float* __restrict__ res){
  int wave=threadIdx.x>>6, lane=threadIdx.x&63;
  int r = blockIdx.x*4+wave;
  if(r>=N_ENT) return;
  float v = agg[(size_t)r*CH+lane];
  float nrm = sqrtf(waveReduceSum(v*v));
  float outv = v / fmaxf(nrm, 1e-12f);
  cur[(size_t)r*CH+lane]=outv;
  res[(size_t)r*CH+lane]+=outv;
}

// ---------------- fused adj writer: zeros + merged knn values, single pass ----------------
// one block per row; no memset, no atomics.
__global__ __launch_bounds__(256) void k_write_adj(
    const int* __restrict__ ki0, const float* __restrict__ kv0,
    const float* __restrict__ rs0,
    const int* __restrict__ ki1, const float* __restrict__ kv1,
    const float* __restrict__ rs1,
    float* __restrict__ adj){
  const int row = blockIdx.x;
  const int t = threadIdx.x;
  __shared__ int   cols[2*TOPKC];
  __shared__ float vals[2*TOPKC];

  if(t < TOPKC){
    int c = ki1[row*TOPKC+t];
    cols[t] = c;
    vals[t] = 0.5f * kv1[row*TOPKC+t] / (sqrtf(rs1[row]) * sqrtf(rs1[c]));
  } else if(t < 2*TOPKC){
    int i = t - TOPKC;
    int c = ki0[row*TOPKC+i];
    cols[t] = c;
    vals[t] = 0.5f * kv0[row*TOPKC+i] / (sqrtf(rs0[row]) * sqrtf(rs0[c]));
  }
  __syncthreads();
  if(t==0){
    // merge duplicates across the two lists (cols within a list are distinct)
    for(int i=TOPKC;i<2*TOPKC;i++){
      int c = cols[i];
      for(int j=0;j<TOPKC;j++){
        if(cols[j]==c){ vals[j]+=vals[i]; cols[i]=-1; break; }
      }
    }
  }
  __syncthreads();

  float4* adj4 = (float4*)(adj + (size_t)row*N_ENT);
#pragma unroll
  for(int k=0;k<8;k++){
    int f = k*256 + t;              // float4 index within row; coalesced
    float4 z = {0.f,0.f,0.f,0.f};
#pragma unroll 1
    for(int e=0;e<2*TOPKC;e++){
      int c = cols[e];
      if(c>=0 && (c>>2)==f){
        float v = vals[e];
        int j = c&3;
        if(j==0) z.x=v; else if(j==1) z.y=v; else if(j==2) z.z=v; else z.w=v;
      }
    }
    adj4[f] = z;
  }
}

extern "C" void kernel_launch(void* const* d_in, const int* in_sizes, int n_in,
                              void* d_out, int out_size, void* d_ws, size_t ws_size,
                              hipStream_t stream){
  const float* user_emb   = (const float*)d_in[0];
  const float* entity_emb = (const float*)d_in[1];
  const int*   edge_index = (const int*)d_in[2];
  const int*   edge_type  = (const int*)d_in[3];
  const int*   inter_idx  = (const int*)d_in[4];
  const float* inter_vals = (const float*)d_in[5];
  const float* W          = (const float*)d_in[6];

  const int* head  = edge_index;
  const int* tail  = edge_index + N_EDGEC;
  const int* irows = inter_idx;
  const int* icols = inter_idx + NNZC;

  float* out     = (float*)d_out;
  float* ent_res = out;
  float* usr_res = out + (size_t)N_ENT*CH;
  float* adj     = out + (size_t)N_ENT*CH + (size_t)N_USR*CH;

  char* wp = (char*)d_ws;
  auto alloc = [&](size_t bytes)->void*{
    void* p = (void*)wp; wp += (bytes+255)/256*256; return p;
  };
  float* cn      = (float*)alloc((size_t)N_ENT*CH*4);
  float* cur_ent = (float*)alloc((size_t)N_ENT*CH*4);
  float* cur_usr = (float*)alloc((size_t)N_USR*CH*4);
  float* agg     = (float*)alloc((size_t)N_ENT*CH*4);
  float* q       = (float*)alloc((size_t)N_ENT*NRELM1*4);
  int*   histE   = (int*)alloc((size_t)N_ENT*4);
  int*   startE  = (int*)alloc((size_t)(N_ENT+1)*4);
  int*   cursorE = (int*)alloc((size_t)N_ENT*4);
  int*   trS     = (int*)alloc((size_t)N_EDGEC*4);
  int*   histU   = (int*)alloc((size_t)N_USR*4);
  int*   startU  = (int*)alloc((size_t)(N_USR+1)*4);
  int*   cursorU = (int*)alloc((size_t)N_USR*4);
  int*   icolsS  = (int*)alloc((size_t)NNZC*4);
  float* ivalsS  = (float*)alloc((size_t)NNZC*4);
  int*   knn_idx0= (int*)alloc((size_t)N_ENT*TOPKC*4);
  float* knn_val0= (float*)alloc((size_t)N_ENT*TOPKC*4);
  float* rowsum0 = (float*)alloc((size_t)N_ENT*4);
  int*   knn_idx1= (int*)alloc((size_t)N_ENT*TOPKC*4);
  float* knn_val1= (float*)alloc((size_t)N_ENT*TOPKC*4);
  float* rowsum1 = (float*)alloc((size_t)N_ENT*4);

  // wbuf for edge softmax lives in the adj output region (256MB, idle during hops)
  float* wbuf = adj;

  // init
  hipMemsetAsync(histE, 0, (size_t)N_ENT*4, stream);
  hipMemsetAsync(histU, 0, (size_t)N_USR*4, stream);
  hipMemcpyAsync(ent_res, entity_emb, (size_t)N_ENT*CH*4, hipMemcpyDeviceToDevice, stream);
  hipMemcpyAsync(usr_res, user_emb,   (size_t)N_USR*CH*4, hipMemcpyDeviceToDevice, stream);
  hipMemcpyAsync(cur_ent, entity_emb, (size_t)N_ENT*CH*4, hipMemcpyDeviceToDevice, stream);
  hipMemcpyAsync(cur_usr, user_emb,   (size_t)N_USR*CH*4, hipMemcpyDeviceToDevice, stream);

  // counting sorts with fused payload gather (edges by head, inter by row)
  k_hist<<<1024,256,0,stream>>>(head, N_EDGEC, histE);
  k_hist<<<512,256,0,stream>>>(irows, NNZC, histU);
  k_scan<<<1,1024,0,stream>>>(histE, startE, cursorE, N_ENT);
  k_scan<<<1,1024,0,stream>>>(histU, startU, cursorU, N_USR);
  k_scatter_sortE<<<1024,256,0,stream>>>(head, tail, edge_type, N_EDGEC, cursorE, trS);
  k_scatter_sortU<<<512,256,0,stream>>>(irows, icols, inter_vals, NNZC, cursorU, icolsS, ivalsS);

  dim3 gg(N_ENT/128, N_ENT/128);

  // build_adj #1 on original entity_emb (sim matrix staged in the adj output region)
  k_rownorm<<<N_ENT/4,256,0,stream>>>(entity_emb, cn, N_ENT, 0.f);
  k_gemm_nt<<<gg,256,0,stream>>>(cn, adj);
  k_topk<<<N_ENT,64,0,stream>>>(adj, knn_idx0, knn_val0, rowsum0);

  // 2 hops
  for(int hop=0; hop<2; ++hop){
    k_q<<<N_ENT/4,256,0,stream>>>(cur_ent, W, q);
    k_edge_agg<<<N_ENT/4,256,0,stream>>>(trS, startE, cur_ent, W, q, wbuf, agg);
    k_user<<<N_USR/4,256,0,stream>>>(icolsS, ivalsS, startU, cur_ent, W, cur_usr, usr_res);
    k_entfin<<<N_ENT/4,256,0,stream>>>(agg, cur_ent, ent_res);
  }

  // build_adj #2 on entity_res_emb
  k_rownorm<<<N_ENT/4,256,0,stream>>>(ent_res, cn, N_ENT, 0.f);
  k_gemm_nt<<<gg,256,0,stream>>>(cn, adj);
  k_topk<<<N_ENT,64,0,stream>>>(adj, knn_idx1, knn_val1, rowsum1);

  // item_adj = 0.5*new + 0.5*origin, single-pass dense write (no memset, no atomics)
  k_write_adj<<<N_ENT,256,0,stream>>>(knn_idx0, knn_val0, rowsum0,
                                      knn_idx1, knn_val1, rowsum1, adj);
}

// Round 6
// 1051.654 us; speedup vs baseline: 1.0143x; 1.0143x over previous
//
#include <hip/hip_runtime.h>
#include <hip/hip_bf16.h>

#define N_ENT   8192
#define N_USR   16384
#define CH      64
#define N_EDGEC 1000000
#define NNZC    500000
#define TOPKC   10
#define NRELM1  8

static __device__ __forceinline__ float waveReduceSum(float v){
#pragma unroll
  for(int o=1;o<64;o<<=1) v += __shfl_xor(v,o,64);
  return v;
}
static __device__ __forceinline__ float waveReduceMax(float v){
#pragma unroll
  for(int o=1;o<64;o<<=1) v = fmaxf(v, __shfl_xor(v,o,64));
  return v;
}
static __device__ __forceinline__ int waveReduceMaxI(int v){
#pragma unroll
  for(int o=1;o<64;o<<=1){ int t=__shfl_xor(v,o,64); v = t>v? t: v; }
  return v;
}
static __device__ __forceinline__ unsigned long long u64max(unsigned long long a, unsigned long long b){
  return a>b? a: b;
}
static __device__ __forceinline__ unsigned mapf(float v){
  unsigned u = __float_as_uint(v);
  return (u & 0x80000000u) ? ~u : (u | 0x80000000u);
}
// linear-value bin for cosine sims in [-1,1]: spreads LDS-atomic traffic
static __device__ __forceinline__ int vbin(float v){
  int b = (int)fmaf(v, 1023.5f, 1023.5f);
  return min(max(b, 0), 2047);
}

// ---------------- sorting (counting sort by segment key) ----------------
__global__ void k_hist(const int* __restrict__ keys, int n, int* __restrict__ hist){
  int i = blockIdx.x*blockDim.x + threadIdx.x;
  int stride = gridDim.x*blockDim.x;
  for(; i<n; i+=stride) atomicAdd(&hist[keys[i]], 1);
}

__global__ __launch_bounds__(1024) void k_scan(const int* __restrict__ hist,
                                               int* __restrict__ start,
                                               int* __restrict__ cursor, int n){
  __shared__ int part[1024];
  int t = threadIdx.x;
  int chunk = n/1024;
  int base = t*chunk;
  int s = 0;
  for(int i=0;i<chunk;i++) s += hist[base+i];
  part[t] = s; __syncthreads();
  for(int off=1; off<1024; off<<=1){
    int v = (t>=off) ? part[t-off] : 0;
    __syncthreads();
    part[t] += v;
    __syncthreads();
  }
  int run = (t==0) ? 0 : part[t-1];
  for(int i=0;i<chunk;i++){
    start[base+i] = run; cursor[base+i] = run;
    run += hist[base+i];
  }
  if(t==1023) start[n] = run;
}

// fused: scatter edges by head, writing packed (tail | rel<<13) at sorted position
__global__ void k_scatter_sortE(const int* __restrict__ head,
                                const int* __restrict__ tail,
                                const int* __restrict__ etype, int n,
                                int* __restrict__ cursor, int* __restrict__ trS){
  int i = blockIdx.x*blockDim.x + threadIdx.x;
  int stride = gridDim.x*blockDim.x;
  for(; i<n; i+=stride){
    int pos = atomicAdd(&cursor[head[i]], 1);
    trS[pos] = (tail[i] & 8191) | ((etype[i]-1)<<13);
  }
}

// fused: scatter interactions by row, writing col + val at sorted position
__global__ void k_scatter_sortU(const int* __restrict__ irows,
                                const int* __restrict__ icols,
                                const float* __restrict__ ivals, int n,
                                int* __restrict__ cursor,
                                int* __restrict__ icolsS, float* __restrict__ ivalsS){
  int i = blockIdx.x*blockDim.x + threadIdx.x;
  int stride = gridDim.x*blockDim.x;
  for(; i<n; i+=stride){
    int pos = atomicAdd(&cursor[irows[i]], 1);
    icolsS[pos] = icols[i];
    ivalsS[pos] = ivals[i];
  }
}

// ---------------- row normalize (cn and l2norm) ----------------
__global__ __launch_bounds__(256) void k_rownorm(const float* __restrict__ in,
                                                 float* __restrict__ out,
                                                 int rows, float eps){
  int wave = threadIdx.x>>6, lane = threadIdx.x&63;
  int r = blockIdx.x*4 + wave;
  if(r>=rows) return;
  float v = in[(size_t)r*CH+lane];
  float ss = waveReduceSum(v*v);
  float nrm = sqrtf(ss);
  out[(size_t)r*CH+lane] = v / fmaxf(nrm, eps);
}

// ---------------- sim GEMM: C = A * A^T, K=64, f32 vector ALU ----------------
__global__ __launch_bounds__(256,2) void k_gemm_nt(const float* __restrict__ A,
                                                   float* __restrict__ C){
  __shared__ float As[CH][132];
  __shared__ float Bs[CH][132];
  const int tid = threadIdx.x;
  const int bi = blockIdx.y*128, bj = blockIdx.x*128;
#pragma unroll
  for(int k=0;k<8;k++){
    int idx = tid + k*256;
    int row = idx>>4;
    int c4  = (idx&15)*4;
    float4 va = ((const float4*)(A + (size_t)(bi+row)*CH))[c4>>2];
    As[c4+0][row]=va.x; As[c4+1][row]=va.y; As[c4+2][row]=va.z; As[c4+3][row]=va.w;
    float4 vb = ((const float4*)(A + (size_t)(bj+row)*CH))[c4>>2];
    Bs[c4+0][row]=vb.x; Bs[c4+1][row]=vb.y; Bs[c4+2][row]=vb.z; Bs[c4+3][row]=vb.w;
  }
  __syncthreads();
  const int tx = tid&15, ty = tid>>4;
  float acc[8][8];
#pragma unroll
  for(int i=0;i<8;i++)
#pragma unroll
    for(int j=0;j<8;j++) acc[i][j]=0.f;
#pragma unroll 8
  for(int k=0;k<CH;k++){
    float4 a0 = *(const float4*)&As[k][ty*8];
    float4 a1 = *(const float4*)&As[k][ty*8+4];
    float4 b0 = *(const float4*)&Bs[k][tx*8];
    float4 b1 = *(const float4*)&Bs[k][tx*8+4];
    float a[8]={a0.x,a0.y,a0.z,a0.w,a1.x,a1.y,a1.z,a1.w};
    float b[8]={b0.x,b0.y,b0.z,b0.w,b1.x,b1.y,b1.z,b1.w};
#pragma unroll
    for(int i=0;i<8;i++)
#pragma unroll
      for(int j=0;j<8;j++) acc[i][j] = fmaf(a[i], b[j], acc[i][j]);
  }
#pragma unroll
  for(int i=0;i<8;i++){
    float4 o0 = {acc[i][0],acc[i][1],acc[i][2],acc[i][3]};
    float4 o1 = {acc[i][4],acc[i][5],acc[i][6],acc[i][7]};
    float* crow = C + (size_t)(bi+ty*8+i)*N_ENT + bj + tx*8;
    *(float4*)crow = o0;
    *((float4*)crow+1) = o1;
  }
}

// ---------------- per-row top-k: radix-select w/ LINEAR bins, one wave per row ----------------
// key = mapped_float<<32 | (0xFFFFFFFF - col): larger wins; ties -> smaller col.
#define CANDCAP 256
__global__ __launch_bounds__(64) void k_topk(const float* __restrict__ S,
                                             int* __restrict__ knn_idx,
                                             float* __restrict__ knn_val,
                                             float* __restrict__ rowsum){
  const int row = blockIdx.x;
  const int lane = threadIdx.x;
  const float4* s4 = (const float4*)(S + (size_t)row*N_ENT);

  __shared__ int hist[2048];
  __shared__ unsigned long long cand[CANDCAP];
  __shared__ int cnt;
#pragma unroll
  for(int i=lane;i<2048;i+=64) hist[i]=0;
  if(lane==0) cnt=0;
  __syncthreads();

  // pass 1: histogram of linear-value bins (sims in [-1,1] -> ~300 busy bins)
  for(int it=0; it<N_ENT/256; ++it){
    float4 v = s4[it*64+lane];
    atomicAdd(&hist[vbin(v.x)],1);
    atomicAdd(&hist[vbin(v.y)],1);
    atomicAdd(&hist[vbin(v.z)],1);
    atomicAdd(&hist[vbin(v.w)],1);
  }
  __syncthreads();

  // find cutoff bin B: smallest bin with cum(>=B) >= TOPKC
  int base = lane*32;
  int s = 0;
#pragma unroll
  for(int j=0;j<32;j++) s += hist[base+j];
  int ss = s;                                   // inclusive suffix over lanes
#pragma unroll
  for(int off=1; off<64; off<<=1){
    int t = __shfl_down(ss, off, 64);
    if(lane+off<64) ss += t;
  }
  int above = ss - s;                           // cum of lanes > this one
  int B_local = 0;
  if(ss >= TOPKC && above < TOPKC){
    int running = above;
    for(int j=31;j>=0;--j){
      running += hist[base+j];
      if(running >= TOPKC){ B_local = base+j; break; }
    }
  }
  int B = waveReduceMaxI(B_local);

  // pass 2: collect candidates (bin >= B) into LDS
  for(int it=0; it<N_ENT/256; ++it){
    int vi = it*64+lane;
    float4 v = s4[vi];
    int c0 = vi*4;
    float vv[4] = {v.x,v.y,v.z,v.w};
#pragma unroll
    for(int j=0;j<4;j++){
      if(vbin(vv[j]) >= B){
        int pos = atomicAdd(&cnt,1);
        if(pos < CANDCAP)
          cand[pos] = ((unsigned long long)mapf(vv[j])<<32)
                    | (unsigned long long)(0xFFFFFFFFu - (unsigned)(c0+j));
      }
    }
  }
  __syncthreads();
  int n = cnt;

  if(n <= CANDCAP){
    unsigned long long c0 = (lane      < n) ? cand[lane]       : 0ull;
    unsigned long long c1 = (lane+64   < n) ? cand[lane+64]    : 0ull;
    unsigned long long c2 = (lane+128  < n) ? cand[lane+128]   : 0ull;
    unsigned long long c3 = (lane+192  < n) ? cand[lane+192]   : 0ull;
    float rs = 0.f;
    for(int sel=0; sel<TOPKC; ++sel){
      unsigned long long m = u64max(u64max(c0,c1), u64max(c2,c3));
#pragma unroll
      for(int o=1;o<64;o<<=1) m = u64max(m, __shfl_xor(m,o,64));
      if(c0==m) c0=0ull; else if(c1==m) c1=0ull;
      else if(c2==m) c2=0ull; else if(c3==m) c3=0ull;
      if(lane==0){
        unsigned mk = (unsigned)(m>>32);
        unsigned uo = (mk & 0x80000000u) ? (mk ^ 0x80000000u) : ~mk;
        float v = __uint_as_float(uo);
        int col = (int)(0xFFFFFFFFu - (unsigned)(m & 0xFFFFFFFFu));
        knn_idx[row*TOPKC+sel] = col;
        knn_val[row*TOPKC+sel] = v;
        rs += v;
      }
    }
    if(lane==0) rowsum[row] = rs;
  } else {
    // pathological fallback: exact register insertion scan (legacy path)
    unsigned long long loc[TOPKC];
#pragma unroll
    for(int i=0;i<TOPKC;i++) loc[i]=0ull;
    for(int it=0; it<N_ENT/256; ++it){
      int vi = it*64+lane;
      float4 v = s4[vi];
      int c0i = vi*4;
      float vv[4] = {v.x,v.y,v.z,v.w};
#pragma unroll
      for(int j=0;j<4;j++){
        unsigned u = mapf(vv[j]);
        unsigned long long key = ((unsigned long long)u<<32)
                               | (unsigned long long)(0xFFFFFFFFu - (unsigned)(c0i+j));
        if(key > loc[TOPKC-1]){
          unsigned long long t = key;
#pragma unroll
          for(int z=0; z<TOPKC; ++z){
            if(t > loc[z]){ unsigned long long tmp=loc[z]; loc[z]=t; t=tmp; }
          }
        }
      }
    }
    float rs = 0.f;
    for(int sel=0; sel<TOPKC; ++sel){
      unsigned long long m = loc[0];
#pragma unroll
      for(int o=1;o<64;o<<=1) m = u64max(m, __shfl_xor(m,o,64));
      if(loc[0] == m){
#pragma unroll
        for(int z=0;z<TOPKC-1;++z) loc[z]=loc[z+1];
        loc[TOPKC-1]=0ull;
      }
      if(lane==0){
        unsigned mk = (unsigned)(m>>32);
        unsigned uo = (mk & 0x80000000u) ? (mk ^ 0x80000000u) : ~mk;
        float v = __uint_as_float(uo);
        int col = (int)(0xFFFFFFFFu - (unsigned)(m & 0xFFFFFFFFu));
        knn_idx[row*TOPKC+sel] = col;
        knn_val[row*TOPKC+sel] = v;
        rs += v;
      }
    }
    if(lane==0) rowsum[row] = rs;
  }
}

// ---------------- q[i][r] = ||ent_i * W_r||^2 ----------------
__global__ __launch_bounds__(256) void k_q(const float* __restrict__ ent,
                                           const float* __restrict__ W,
                                           float* __restrict__ q){
  int wave=threadIdx.x>>6, lane=threadIdx.x&63;
  int r = blockIdx.x*4+wave;
  if(r>=N_ENT) return;
  float x = ent[(size_t)r*CH+lane];
#pragma unroll
  for(int rel=0; rel<NRELM1; rel++){
    float tt = x*W[rel*CH+lane];
    float s = waveReduceSum(tt*tt);
    if(lane==0) q[r*NRELM1+rel]=s;
  }
}

// ---------------- per-head edge aggregation (contiguous sorted arrays) ----------------
__global__ __launch_bounds__(256) void k_edge_agg(
    const int* __restrict__ trS, const int* __restrict__ startE,
    const float* __restrict__ ent, const float* __restrict__ W,
    const float* __restrict__ q, float* __restrict__ wbuf,
    float* __restrict__ agg){
  int wave=threadIdx.x>>6, lane=threadIdx.x&63;
  int h = blockIdx.x*4+wave;
  if(h>=N_ENT) return;
  int s = startE[h], e2 = startE[h+1];

  float qh[NRELM1];
#pragma unroll
  for(int r=0;r<NRELM1;r++) qh[r] = q[h*NRELM1+r];

  float mx = 0.f;
  for(int p=s+lane; p<e2; p+=64){
    int tr = trS[p];
    int tl = tr & 8191, r = tr>>13;
    float att = qh[r]*q[tl*NRELM1+r];
    wbuf[p] = att;
    mx = fmaxf(mx, att);
  }
  mx = waveReduceMax(mx);

  float dn = 0.f;
  for(int p=s+lane; p<e2; p+=64){
    float e = expf(wbuf[p]-mx);
    wbuf[p] = e;
    dn += e;
  }
  dn = waveReduceSum(dn);
  float inv = (dn>0.f) ? 1.f/dn : 0.f;

  float wr[NRELM1];
#pragma unroll
  for(int r=0;r<NRELM1;r++) wr[r] = W[r*CH+lane];
  float acc = 0.f;
  for(int p=s; p<e2; p++){
    int tr = trS[p];
    int tl = tr & 8191, r = tr>>13;
    float wgt = wbuf[p]*inv;
    acc = fmaf(wgt*wr[r], ent[(size_t)tl*CH+lane], acc);
  }
  agg[(size_t)h*CH+lane] = acc;
}

// ---------------- per-user: sparse agg + gated score + l2norm + residual ----------------
__global__ __launch_bounds__(256) void k_user(
    const int* __restrict__ icolsS, const float* __restrict__ ivalsS,
    const int* __restrict__ startU,
    const float* __restrict__ ent, const float* __restrict__ W,
    float* __restrict__ usr, float* __restrict__ usr_res){
  int wave=threadIdx.x>>6, lane=threadIdx.x&63;
  int u = blockIdx.x*4+wave;
  if(u>=N_USR) return;
  float ue = usr[(size_t)u*CH+lane];
  float l[NRELM1];
#pragma unroll
  for(int r=0;r<NRELM1;r++) l[r] = waveReduceSum(ue*W[r*CH+lane]);
  float lm = l[0];
#pragma unroll
  for(int r=1;r<NRELM1;r++) lm = fmaxf(lm,l[r]);
  float se=0.f;
#pragma unroll
  for(int r=0;r<NRELM1;r++){ l[r]=expf(l[r]-lm); se+=l[r]; }
  float inv = 1.f/se;
  float g = 0.f;
#pragma unroll
  for(int r=0;r<NRELM1;r++) g = fmaf(l[r]*inv, W[r*CH+lane], g);
  float acc=0.f;
  int s=startU[u], e2=startU[u+1];
  for(int p=s;p<e2;p++){
    acc = fmaf(ivalsS[p], ent[(size_t)icolsS[p]*CH+lane], acc);
  }
  float res = acc*(1.f+g);
  float nrm = sqrtf(waveReduceSum(res*res));
  float outv = res / fmaxf(nrm, 1e-12f);
  usr_res[(size_t)u*CH+lane] += outv;
  usr[(size_t)u*CH+lane] = outv;
}

// ---------------- entity finalize: l2norm + residual ----------------
__global__ __launch_bounds__(256) void k_entfin(const float* __restrict__ agg,
                                                float* __restrict__ cur,
                                                float* __restrict__ res){
  int wave=threadIdx.x>>6, lane=threadIdx.x&63;
  int r = blockIdx.x*4+wave;
  if(r>=N_ENT) return;
  float v = agg[(size_t)r*CH+lane];
  float nrm = sqrtf(waveReduceSum(v*v));
  float outv = v / fmaxf(nrm, 1e-12f);
  cur[(size_t)r*CH+lane]=outv;
  res[(size_t)r*CH+lane]+=outv;
}

// ---------------- fused adj writer: zeros + merged knn values, single pass ----------------
__global__ __launch_bounds__(256) void k_write_adj(
    const int* __restrict__ ki0, const float* __restrict__ kv0,
    const float* __restrict__ rs0,
    const int* __restrict__ ki1, const float* __restrict__ kv1,
    const float* __restrict__ rs1,
    float* __restrict__ adj){
  const int row = blockIdx.x;
  const int t = threadIdx.x;
  __shared__ int   cols[2*TOPKC];
  __shared__ float vals[2*TOPKC];

  if(t < TOPKC){
    int c = ki1[row*TOPKC+t];
    cols[t] = c;
    vals[t] = 0.5f * kv1[row*TOPKC+t] / (sqrtf(rs1[row]) * sqrtf(rs1[c]));
  } else if(t < 2*TOPKC){
    int i = t - TOPKC;
    int c = ki0[row*TOPKC+i];
    cols[t] = c;
    vals[t] = 0.5f * kv0[row*TOPKC+i] / (sqrtf(rs0[row]) * sqrtf(rs0[c]));
  }
  __syncthreads();
  if(t==0){
    for(int i=TOPKC;i<2*TOPKC;i++){
      int c = cols[i];
      for(int j=0;j<TOPKC;j++){
        if(cols[j]==c){ vals[j]+=vals[i]; cols[i]=-1; break; }
      }
    }
  }
  __syncthreads();

  float4* adj4 = (float4*)(adj + (size_t)row*N_ENT);
#pragma unroll
  for(int k=0;k<8;k++){
    int f = k*256 + t;
    float4 z = {0.f,0.f,0.f,0.f};
#pragma unroll 1
    for(int e=0;e<2*TOPKC;e++){
      int c = cols[e];
      if(c>=0 && (c>>2)==f){
        float v = vals[e];
        int j = c&3;
        if(j==0) z.x=v; else if(j==1) z.y=v; else if(j==2) z.z=v; else z.w=v;
      }
    }
    adj4[f] = z;
  }
}

extern "C" void kernel_launch(void* const* d_in, const int* in_sizes, int n_in,
                              void* d_out, int out_size, void* d_ws, size_t ws_size,
                              hipStream_t stream){
  const float* user_emb   = (const float*)d_in[0];
  const float* entity_emb = (const float*)d_in[1];
  const int*   edge_index = (const int*)d_in[2];
  const int*   edge_type  = (const int*)d_in[3];
  const int*   inter_idx  = (const int*)d_in[4];
  const float* inter_vals = (const float*)d_in[5];
  const float* W          = (const float*)d_in[6];

  const int* head  = edge_index;
  const int* tail  = edge_index + N_EDGEC;
  const int* irows = inter_idx;
  const int* icols = inter_idx + NNZC;

  float* out     = (float*)d_out;
  float* ent_res = out;
  float* usr_res = out + (size_t)N_ENT*CH;
  float* adj     = out + (size_t)N_ENT*CH + (size_t)N_USR*CH;

  char* wp = (char*)d_ws;
  auto alloc = [&](size_t bytes)->void*{
    void* p = (void*)wp; wp += (bytes+255)/256*256; return p;
  };
  float* cn      = (float*)alloc((size_t)N_ENT*CH*4);
  float* cur_ent = (float*)alloc((size_t)N_ENT*CH*4);
  float* cur_usr = (float*)alloc((size_t)N_USR*CH*4);
  float* agg     = (float*)alloc((size_t)N_ENT*CH*4);
  float* q       = (float*)alloc((size_t)N_ENT*NRELM1*4);
  int*   histE   = (int*)alloc((size_t)N_ENT*4);
  int*   startE  = (int*)alloc((size_t)(N_ENT+1)*4);
  int*   cursorE = (int*)alloc((size_t)N_ENT*4);
  int*   trS     = (int*)alloc((size_t)N_EDGEC*4);
  int*   histU   = (int*)alloc((size_t)N_USR*4);
  int*   startU  = (int*)alloc((size_t)(N_USR+1)*4);
  int*   cursorU = (int*)alloc((size_t)N_USR*4);
  int*   icolsS  = (int*)alloc((size_t)NNZC*4);
  float* ivalsS  = (float*)alloc((size_t)NNZC*4);
  int*   knn_idx0= (int*)alloc((size_t)N_ENT*TOPKC*4);
  float* knn_val0= (float*)alloc((size_t)N_ENT*TOPKC*4);
  float* rowsum0 = (float*)alloc((size_t)N_ENT*4);
  int*   knn_idx1= (int*)alloc((size_t)N_ENT*TOPKC*4);
  float* knn_val1= (float*)alloc((size_t)N_ENT*TOPKC*4);
  float* rowsum1 = (float*)alloc((size_t)N_ENT*4);

  // wbuf for edge softmax lives in the adj output region (256MB, idle during hops)
  float* wbuf = adj;

  // init
  hipMemsetAsync(histE, 0, (size_t)N_ENT*4, stream);
  hipMemsetAsync(histU, 0, (size_t)N_USR*4, stream);
  hipMemcpyAsync(ent_res, entity_emb, (size_t)N_ENT*CH*4, hipMemcpyDeviceToDevice, stream);
  hipMemcpyAsync(usr_res, user_emb,   (size_t)N_USR*CH*4, hipMemcpyDeviceToDevice, stream);
  hipMemcpyAsync(cur_ent, entity_emb, (size_t)N_ENT*CH*4, hipMemcpyDeviceToDevice, stream);
  hipMemcpyAsync(cur_usr, user_emb,   (size_t)N_USR*CH*4, hipMemcpyDeviceToDevice, stream);

  // counting sorts with fused payload gather (edges by head, inter by row)
  k_hist<<<1024,256,0,stream>>>(head, N_EDGEC, histE);
  k_hist<<<512,256,0,stream>>>(irows, NNZC, histU);
  k_scan<<<1,1024,0,stream>>>(histE, startE, cursorE, N_ENT);
  k_scan<<<1,1024,0,stream>>>(histU, startU, cursorU, N_USR);
  k_scatter_sortE<<<1024,256,0,stream>>>(head, tail, edge_type, N_EDGEC, cursorE, trS);
  k_scatter_sortU<<<512,256,0,stream>>>(irows, icols, inter_vals, NNZC, cursorU, icolsS, ivalsS);

  dim3 gg(N_ENT/128, N_ENT/128);

  // build_adj #1 on original entity_emb (sim matrix staged in the adj output region)
  k_rownorm<<<N_ENT/4,256,0,stream>>>(entity_emb, cn, N_ENT, 0.f);
  k_gemm_nt<<<gg,256,0,stream>>>(cn, adj);
  k_topk<<<N_ENT,64,0,stream>>>(adj, knn_idx0, knn_val0, rowsum0);

  // 2 hops
  for(int hop=0; hop<2; ++hop){
    k_q<<<N_ENT/4,256,0,stream>>>(cur_ent, W, q);
    k_edge_agg<<<N_ENT/4,256,0,stream>>>(trS, startE, cur_ent, W, q, wbuf, agg);
    k_user<<<N_USR/4,256,0,stream>>>(icolsS, ivalsS, startU, cur_ent, W, cur_usr, usr_res);
    k_entfin<<<N_ENT/4,256,0,stream>>>(agg, cur_ent, ent_res);
  }

  // build_adj #2 on entity_res_emb
  k_rownorm<<<N_ENT/4,256,0,stream>>>(ent_res, cn, N_ENT, 0.f);
  k_gemm_nt<<<gg,256,0,stream>>>(cn, adj);
  k_topk<<<N_ENT,64,0,stream>>>(adj, knn_idx1, knn_val1, rowsum1);

  // item_adj = 0.5*new + 0.5*origin, single-pass dense write (no memset, no atomics)
  k_write_adj<<<N_ENT,256,0,stream>>>(knn_idx0, knn_val0, rowsum0,
                                      knn_idx1, knn_val1, rowsum1, adj);
}

// Round 8
// 999.813 us; speedup vs baseline: 1.0669x; 1.0519x over previous
//
#include <hip/hip_runtime.h>
#include <hip/hip_bf16.h>

#define N_ENT   8192
#define N_USR   16384
#define CH      64
#define N_EDGEC 1000000
#define NNZC    500000
#define TOPKC   10
#define NRELM1  8
#define KSPLIT  384   // 6 limb-blocks of 64: A=[h,h,m,l,h,m], B=[h,m,h,h,l,m]
#define BKS     96    // K-step (4 steps of 96)

typedef __bf16 bf16x8 __attribute__((ext_vector_type(8)));
typedef float  f32x4  __attribute__((ext_vector_type(4)));

static __device__ __forceinline__ float waveReduceSum(float v){
#pragma unroll
  for(int o=1;o<64;o<<=1) v += __shfl_xor(v,o,64);
  return v;
}
static __device__ __forceinline__ float waveReduceMax(float v){
#pragma unroll
  for(int o=1;o<64;o<<=1) v = fmaxf(v, __shfl_xor(v,o,64));
  return v;
}
static __device__ __forceinline__ int waveReduceMaxI(int v){
#pragma unroll
  for(int o=1;o<64;o<<=1){ int t=__shfl_xor(v,o,64); v = t>v? t: v; }
  return v;
}
static __device__ __forceinline__ unsigned long long u64max(unsigned long long a, unsigned long long b){
  return a>b? a: b;
}
static __device__ __forceinline__ unsigned mapf(float v){
  unsigned u = __float_as_uint(v);
  return (u & 0x80000000u) ? ~u : (u | 0x80000000u);
}
// linear-value bin for cosine sims in [-1,1]
static __device__ __forceinline__ int vbin(float v){
  int b = (int)fmaf(v, 1023.5f, 1023.5f);
  return min(max(b, 0), 2047);
}
// f32 -> bf16 RTN-even (inputs finite)
static __device__ __forceinline__ ushort f2bf(float x){
  unsigned u = __float_as_uint(x);
  return (ushort)((u + 0x7FFFu + ((u>>16)&1u)) >> 16);
}
static __device__ __forceinline__ float bf2f(ushort h){
  return __uint_as_float((unsigned)h<<16);
}

// ---------------- sorting (counting sort by segment key) ----------------
__global__ void k_hist(const int* __restrict__ keys, int n, int* __restrict__ hist){
  int i = blockIdx.x*blockDim.x + threadIdx.x;
  int stride = gridDim.x*blockDim.x;
  for(; i<n; i+=stride) atomicAdd(&hist[keys[i]], 1);
}

__global__ __launch_bounds__(1024) void k_scan(const int* __restrict__ hist,
                                               int* __restrict__ start,
                                               int* __restrict__ cursor, int n){
  __shared__ int part[1024];
  int t = threadIdx.x;
  int chunk = n/1024;
  int base = t*chunk;
  int s = 0;
  for(int i=0;i<chunk;i++) s += hist[base+i];
  part[t] = s; __syncthreads();
  for(int off=1; off<1024; off<<=1){
    int v = (t>=off) ? part[t-off] : 0;
    __syncthreads();
    part[t] += v;
    __syncthreads();
  }
  int run = (t==0) ? 0 : part[t-1];
  for(int i=0;i<chunk;i++){
    start[base+i] = run; cursor[base+i] = run;
    run += hist[base+i];
  }
  if(t==1023) start[n] = run;
}

__global__ void k_scatter_sortE(const int* __restrict__ head,
                                const int* __restrict__ tail,
                                const int* __restrict__ etype, int n,
                                int* __restrict__ cursor, int* __restrict__ trS){
  int i = blockIdx.x*blockDim.x + threadIdx.x;
  int stride = gridDim.x*blockDim.x;
  for(; i<n; i+=stride){
    int pos = atomicAdd(&cursor[head[i]], 1);
    trS[pos] = (tail[i] & 8191) | ((etype[i]-1)<<13);
  }
}

__global__ void k_scatter_sortU(const int* __restrict__ irows,
                                const int* __restrict__ icols,
                                const float* __restrict__ ivals, int n,
                                int* __restrict__ cursor,
                                int* __restrict__ icolsS, float* __restrict__ ivalsS){
  int i = blockIdx.x*blockDim.x + threadIdx.x;
  int stride = gridDim.x*blockDim.x;
  for(; i<n; i+=stride){
    int pos = atomicAdd(&cursor[irows[i]], 1);
    icolsS[pos] = icols[i];
    ivalsS[pos] = ivals[i];
  }
}

// ---------------- normalize + triple-bf16 split into A/B limb layouts ----------------
// x = h + m + l (exact residual splits). A=[h,h,m,l,h,m], B=[h,m,h,h,l,m]:
// sum of block products = h.h + h.m + m.h + l.h + h.l + m.m  (residual ~1e-8)
__global__ __launch_bounds__(256) void k_split(const float* __restrict__ in,
                                               ushort* __restrict__ outA,
                                               ushort* __restrict__ outB){
  int wave = threadIdx.x>>6, lane = threadIdx.x&63;
  int r = blockIdx.x*4 + wave;
  float v = in[(size_t)r*CH+lane];
  float ss = waveReduceSum(v*v);
  float x = v / sqrtf(ss);
  ushort h = f2bf(x);
  float r1 = x - bf2f(h);
  ushort m = f2bf(r1);
  float r2 = r1 - bf2f(m);
  ushort l = f2bf(r2);
  ushort* oA = outA + (size_t)r*KSPLIT;
  ushort* oB = outB + (size_t)r*KSPLIT;
  oA[lane]     =h; oA[64+lane] =h; oA[128+lane]=m;
  oA[192+lane] =l; oA[256+lane]=h; oA[320+lane]=m;
  oB[lane]     =h; oB[64+lane] =m; oB[128+lane]=h;
  oB[192+lane] =h; oB[256+lane]=l; oB[320+lane]=m;
}

// ---------------- sim GEMM: C = Ã * B̃^T via bf16 MFMA, K=384 ----------------
// 128x128 tile, 4 waves in 2x2, 4x4 16x16 fragments per wave, BK=96 (4 steps).
__global__ __launch_bounds__(256) void k_gemm_bf16(const ushort* __restrict__ A,
                                                   const ushort* __restrict__ B,
                                                   float* __restrict__ C){
  __shared__ ushort As[128*BKS];
  __shared__ ushort Bs[128*BKS];
  const int tid = threadIdx.x, lane = tid&63, wid = tid>>6;
  const int bi = blockIdx.y*128, bj = blockIdx.x*128;
  const int wr = (wid>>1)*64, wc = (wid&1)*64;
  const int r16 = lane&15, kg = lane>>4;

  f32x4 acc[4][4] = {};

  const uint4* gA = (const uint4*)A + (size_t)bi*(KSPLIT/8);
  const uint4* gB = (const uint4*)B + (size_t)bj*(KSPLIT/8);
  const int row2 = tid>>1, half = tid&1;

  for(int s=0; s<KSPLIT/BKS; ++s){
    __syncthreads();
#pragma unroll
    for(int jj=0;jj<6;jj++){
      *(uint4*)&As[row2*BKS + half*48 + jj*8] = gA[row2*(KSPLIT/8) + s*12 + half*6 + jj];
      *(uint4*)&Bs[row2*BKS + half*48 + jj*8] = gB[row2*(KSPLIT/8) + s*12 + half*6 + jj];
    }
    __syncthreads();
#pragma unroll
    for(int kk=0;kk<3;kk++){
      bf16x8 a[4], b[4];
#pragma unroll
      for(int m=0;m<4;m++)
        a[m] = *(const bf16x8*)&As[(wr+m*16+r16)*BKS + kk*32 + kg*8];
#pragma unroll
      for(int n=0;n<4;n++)
        b[n] = *(const bf16x8*)&Bs[(wc+n*16+r16)*BKS + kk*32 + kg*8];
#pragma unroll
      for(int m=0;m<4;m++)
#pragma unroll
        for(int n=0;n<4;n++)
          acc[m][n] = __builtin_amdgcn_mfma_f32_16x16x32_bf16(a[m], b[n], acc[m][n], 0,0,0);
    }
  }

  // C/D layout: col = lane&15, row = (lane>>4)*4 + reg  (m89-verified)
#pragma unroll
  for(int m=0;m<4;m++){
#pragma unroll
    for(int n=0;n<4;n++){
      size_t base = (size_t)(bi + wr + m*16 + kg*4)*N_ENT + (bj + wc + n*16 + r16);
      C[base]          = acc[m][n][0];
      C[base+N_ENT]    = acc[m][n][1];
      C[base+2*N_ENT]  = acc[m][n][2];
      C[base+3*N_ENT]  = acc[m][n][3];
    }
  }
}

// ---------------- per-row top-k: radix-select w/ LINEAR bins, one wave per row ----------------
#define CANDCAP 256
__global__ __launch_bounds__(64) void k_topk(const float* __restrict__ S,
                                             int* __restrict__ knn_idx,
                                             float* __restrict__ knn_val,
                                             float* __restrict__ rowsum){
  const int row = blockIdx.x;
  const int lane = threadIdx.x;
  const float4* s4 = (const float4*)(S + (size_t)row*N_ENT);

  __shared__ int hist[2048];
  __shared__ unsigned long long cand[CANDCAP];
  __shared__ int cnt;
#pragma unroll
  for(int i=lane;i<2048;i+=64) hist[i]=0;
  if(lane==0) cnt=0;
  __syncthreads();

  for(int it=0; it<N_ENT/256; ++it){
    float4 v = s4[it*64+lane];
    atomicAdd(&hist[vbin(v.x)],1);
    atomicAdd(&hist[vbin(v.y)],1);
    atomicAdd(&hist[vbin(v.z)],1);
    atomicAdd(&hist[vbin(v.w)],1);
  }
  __syncthreads();

  int base = lane*32;
  int s = 0;
#pragma unroll
  for(int j=0;j<32;j++) s += hist[base+j];
  int ss = s;
#pragma unroll
  for(int off=1; off<64; off<<=1){
    int t = __shfl_down(ss, off, 64);
    if(lane+off<64) ss += t;
  }
  int above = ss - s;
  int B_local = 0;
  if(ss >= TOPKC && above < TOPKC){
    int running = above;
    for(int j=31;j>=0;--j){
      running += hist[base+j];
      if(running >= TOPKC){ B_local = base+j; break; }
    }
  }
  int B = waveReduceMaxI(B_local);

  for(int it=0; it<N_ENT/256; ++it){
    int vi = it*64+lane;
    float4 v = s4[vi];
    int c0 = vi*4;
    float vv[4] = {v.x,v.y,v.z,v.w};
#pragma unroll
    for(int j=0;j<4;j++){
      if(vbin(vv[j]) >= B){
        int pos = atomicAdd(&cnt,1);
        if(pos < CANDCAP)
          cand[pos] = ((unsigned long long)mapf(vv[j])<<32)
                    | (unsigned long long)(0xFFFFFFFFu - (unsigned)(c0+j));
      }
    }
  }
  __syncthreads();
  int n = cnt;

  if(n <= CANDCAP){
    unsigned long long c0 = (lane      < n) ? cand[lane]       : 0ull;
    unsigned long long c1 = (lane+64   < n) ? cand[lane+64]    : 0ull;
    unsigned long long c2 = (lane+128  < n) ? cand[lane+128]   : 0ull;
    unsigned long long c3 = (lane+192  < n) ? cand[lane+192]   : 0ull;
    float rs = 0.f;
    for(int sel=0; sel<TOPKC; ++sel){
      unsigned long long m = u64max(u64max(c0,c1), u64max(c2,c3));
#pragma unroll
      for(int o=1;o<64;o<<=1) m = u64max(m, __shfl_xor(m,o,64));
      if(c0==m) c0=0ull; else if(c1==m) c1=0ull;
      else if(c2==m) c2=0ull; else if(c3==m) c3=0ull;
      if(lane==0){
        unsigned mk = (unsigned)(m>>32);
        unsigned uo = (mk & 0x80000000u) ? (mk ^ 0x80000000u) : ~mk;
        float v = __uint_as_float(uo);
        int col = (int)(0xFFFFFFFFu - (unsigned)(m & 0xFFFFFFFFu));
        knn_idx[row*TOPKC+sel] = col;
        knn_val[row*TOPKC+sel] = v;
        rs += v;
      }
    }
    if(lane==0) rowsum[row] = rs;
  } else {
    unsigned long long loc[TOPKC];
#pragma unroll
    for(int i=0;i<TOPKC;i++) loc[i]=0ull;
    for(int it=0; it<N_ENT/256; ++it){
      int vi = it*64+lane;
      float4 v = s4[vi];
      int c0i = vi*4;
      float vv[4] = {v.x,v.y,v.z,v.w};
#pragma unroll
      for(int j=0;j<4;j++){
        unsigned u = mapf(vv[j]);
        unsigned long long key = ((unsigned long long)u<<32)
                               | (unsigned long long)(0xFFFFFFFFu - (unsigned)(c0i+j));
        if(key > loc[TOPKC-1]){
          unsigned long long t = key;
#pragma unroll
          for(int z=0; z<TOPKC; ++z){
            if(t > loc[z]){ unsigned long long tmp=loc[z]; loc[z]=t; t=tmp; }
          }
        }
      }
    }
    float rs = 0.f;
    for(int sel=0; sel<TOPKC; ++sel){
      unsigned long long m = loc[0];
#pragma unroll
      for(int o=1;o<64;o<<=1) m = u64max(m, __shfl_xor(m,o,64));
      if(loc[0] == m){
#pragma unroll
        for(int z=0;z<TOPKC-1;++z) loc[z]=loc[z+1];
        loc[TOPKC-1]=0ull;
      }
      if(lane==0){
        unsigned mk = (unsigned)(m>>32);
        unsigned uo = (mk & 0x80000000u) ? (mk ^ 0x80000000u) : ~mk;
        float v = __uint_as_float(uo);
        int col = (int)(0xFFFFFFFFu - (unsigned)(m & 0xFFFFFFFFu));
        knn_idx[row*TOPKC+sel] = col;
        knn_val[row*TOPKC+sel] = v;
        rs += v;
      }
    }
    if(lane==0) rowsum[row] = rs;
  }
}

// ---------------- q[i][r] = ||ent_i * W_r||^2 ----------------
__global__ __launch_bounds__(256) void k_q(const float* __restrict__ ent,
                                           const float* __restrict__ W,
                                           float* __restrict__ q){
  int wave=threadIdx.x>>6, lane=threadIdx.x&63;
  int r = blockIdx.x*4+wave;
  if(r>=N_ENT) return;
  float x = ent[(size_t)r*CH+lane];
#pragma unroll
  for(int rel=0; rel<NRELM1; rel++){
    float tt = x*W[rel*CH+lane];
    float s = waveReduceSum(tt*tt);
    if(lane==0) q[r*NRELM1+rel]=s;
  }
}

// ---------------- per-head edge aggregation (contiguous sorted arrays) ----------------
__global__ __launch_bounds__(256) void k_edge_agg(
    const int* __restrict__ trS, const int* __restrict__ startE,
    const float* __restrict__ ent, const float* __restrict__ W,
    const float* __restrict__ q, float* __restrict__ wbuf,
    float* __restrict__ agg){
  int wave=threadIdx.x>>6, lane=threadIdx.x&63;
  int h = blockIdx.x*4+wave;
  if(h>=N_ENT) return;
  int s = startE[h], e2 = startE[h+1];

  float qh[NRELM1];
#pragma unroll
  for(int r=0;r<NRELM1;r++) qh[r] = q[h*NRELM1+r];

  float mx = 0.f;
  for(int p=s+lane; p<e2; p+=64){
    int tr = trS[p];
    int tl = tr & 8191, r = tr>>13;
    float att = qh[r]*q[tl*NRELM1+r];
    wbuf[p] = att;
    mx = fmaxf(mx, att);
  }
  mx = waveReduceMax(mx);

  float dn = 0.f;
  for(int p=s+lane; p<e2; p+=64){
    float e = expf(wbuf[p]-mx);
    wbuf[p] = e;
    dn += e;
  }
  dn = waveReduceSum(dn);
  float inv = (dn>0.f) ? 1.f/dn : 0.f;

  float wr[NRELM1];
#pragma unroll
  for(int r=0;r<NRELM1;r++) wr[r] = W[r*CH+lane];
  float acc = 0.f;
  for(int p=s; p<e2; p++){
    int tr = trS[p];
    int tl = tr & 8191, r = tr>>13;
    float wgt = wbuf[p]*inv;
    acc = fmaf(wgt*wr[r], ent[(size_t)tl*CH+lane], acc);
  }
  agg[(size_t)h*CH+lane] = acc;
}

// ---------------- per-user: sparse agg + gated score + l2norm + residual ----------------
__global__ __launch_bounds__(256) void k_user(
    const int* __restrict__ icolsS, const float* __restrict__ ivalsS,
    const int* __restrict__ startU,
    const float* __restrict__ ent, const float* __restrict__ W,
    float* __restrict__ usr, float* __restrict__ usr_res){
  int wave=threadIdx.x>>6, lane=threadIdx.x&63;
  int u = blockIdx.x*4+wave;
  if(u>=N_USR) return;
  float ue = usr[(size_t)u*CH+lane];
  float l[NRELM1];
#pragma unroll
  for(int r=0;r<NRELM1;r++) l[r] = waveReduceSum(ue*W[r*CH+lane]);
  float lm = l[0];
#pragma unroll
  for(int r=1;r<NRELM1;r++) lm = fmaxf(lm,l[r]);
  float se=0.f;
#pragma unroll
  for(int r=0;r<NRELM1;r++){ l[r]=expf(l[r]-lm); se+=l[r]; }
  float inv = 1.f/se;
  float g = 0.f;
#pragma unroll
  for(int r=0;r<NRELM1;r++) g = fmaf(l[r]*inv, W[r*CH+lane], g);
  float acc=0.f;
  int s=startU[u], e2=startU[u+1];
  for(int p=s;p<e2;p++){
    acc = fmaf(ivalsS[p], ent[(size_t)icolsS[p]*CH+lane], acc);
  }
  float res = acc*(1.f+g);
  float nrm = sqrtf(waveReduceSum(res*res));
  float outv = res / fmaxf(nrm, 1e-12f);
  usr_res[(size_t)u*CH+lane] += outv;
  usr[(size_t)u*CH+lane] = outv;
}

// ---------------- entity finalize: l2norm + residual ----------------
__global__ __launch_bounds__(256) void k_entfin(const float* __restrict__ agg,
                                                float* __restrict__ cur,
                                                float* __restrict__ res){
  int wave=threadIdx.x>>6, lane=threadIdx.x&63;
  int r = blockIdx.x*4+wave;
  if(r>=N_ENT) return;
  float v = agg[(size_t)r*CH+lane];
  float nrm = sqrtf(waveReduceSum(v*v));
  float outv = v / fmaxf(nrm, 1e-12f);
  cur[(size_t)r*CH+lane]=outv;
  res[(size_t)r*CH+lane]+=outv;
}

// ---------------- fused adj writer: coalesced zeros, then direct patch ----------------
__global__ __launch_bounds__(256) void k_write_adj(
    const int* __restrict__ ki0, const float* __restrict__ kv0,
    const float* __restrict__ rs0,
    const int* __restrict__ ki1, const float* __restrict__ kv1,
    const float* __restrict__ rs1,
    float* __restrict__ adj){
  const int row = blockIdx.x;
  const int t = threadIdx.x;
  __shared__ int   cols[2*TOPKC];
  __shared__ float vals[2*TOPKC];

  if(t < TOPKC){
    int c = ki1[row*TOPKC+t];
    cols[t] = c;
    vals[t] = 0.5f * kv1[row*TOPKC+t] / (sqrtf(rs1[row]) * sqrtf(rs1[c]));
  } else if(t < 2*TOPKC){
    int i = t - TOPKC;
    int c = ki0[row*TOPKC+i];
    cols[t] = c;
    vals[t] = 0.5f * kv0[row*TOPKC+i] / (sqrtf(rs0[row]) * sqrtf(rs0[c]));
  }
  __syncthreads();
  if(t==0){
    for(int i=TOPKC;i<2*TOPKC;i++){
      int c = cols[i];
      for(int j=0;j<TOPKC;j++){
        if(cols[j]==c){ vals[j]+=vals[i]; cols[i]=-1; break; }
      }
    }
  }
  __syncthreads();

  float4* adj4 = (float4*)(adj + (size_t)row*N_ENT);
  float4 z = {0.f,0.f,0.f,0.f};
#pragma unroll
  for(int k=0;k<8;k++) adj4[k*256 + t] = z;
  __syncthreads();   // block-scope memory barrier: zeros ordered before patch
  if(t < 2*TOPKC){
    int c = cols[t];
    if(c >= 0) adj[(size_t)row*N_ENT + c] = vals[t];
  }
}

extern "C" void kernel_launch(void* const* d_in, const int* in_sizes, int n_in,
                              void* d_out, int out_size, void* d_ws, size_t ws_size,
                              hipStream_t stream){
  const float* user_emb   = (const float*)d_in[0];
  const float* entity_emb = (const float*)d_in[1];
  const int*   edge_index = (const int*)d_in[2];
  const int*   edge_type  = (const int*)d_in[3];
  const int*   inter_idx  = (const int*)d_in[4];
  const float* inter_vals = (const float*)d_in[5];
  const float* W          = (const float*)d_in[6];

  const int* head  = edge_index;
  const int* tail  = edge_index + N_EDGEC;
  const int* irows = inter_idx;
  const int* icols = inter_idx + NNZC;

  float* out     = (float*)d_out;
  float* ent_res = out;
  float* usr_res = out + (size_t)N_ENT*CH;
  float* adj     = out + (size_t)N_ENT*CH + (size_t)N_USR*CH;

  char* wp = (char*)d_ws;
  auto alloc = [&](size_t bytes)->void*{
    void* p = (void*)wp; wp += (bytes+255)/256*256; return p;
  };
  ushort* abufA  = (ushort*)alloc((size_t)N_ENT*KSPLIT*2);
  ushort* abufB  = (ushort*)alloc((size_t)N_ENT*KSPLIT*2);
  float* cur_ent = (float*)alloc((size_t)N_ENT*CH*4);
  float* cur_usr = (float*)alloc((size_t)N_USR*CH*4);
  float* agg     = (float*)alloc((size_t)N_ENT*CH*4);
  float* q       = (float*)alloc((size_t)N_ENT*NRELM1*4);
  int*   histE   = (int*)alloc((size_t)N_ENT*4);
  int*   startE  = (int*)alloc((size_t)(N_ENT+1)*4);
  int*   cursorE = (int*)alloc((size_t)N_ENT*4);
  int*   trS     = (int*)alloc((size_t)N_EDGEC*4);
  int*   histU   = (int*)alloc((size_t)N_USR*4);
  int*   startU  = (int*)alloc((size_t)(N_USR+1)*4);
  int*   cursorU = (int*)alloc((size_t)N_USR*4);
  int*   icolsS  = (int*)alloc((size_t)NNZC*4);
  float* ivalsS  = (float*)alloc((size_t)NNZC*4);
  int*   knn_idx0= (int*)alloc((size_t)N_ENT*TOPKC*4);
  float* knn_val0= (float*)alloc((size_t)N_ENT*TOPKC*4);
  float* rowsum0 = (float*)alloc((size_t)N_ENT*4);
  int*   knn_idx1= (int*)alloc((size_t)N_ENT*TOPKC*4);
  float* knn_val1= (float*)alloc((size_t)N_ENT*TOPKC*4);
  float* rowsum1 = (float*)alloc((size_t)N_ENT*4);

  // wbuf for edge softmax lives in the adj output region (256MB, idle during hops)
  float* wbuf = adj;

  // init
  hipMemsetAsync(histE, 0, (size_t)N_ENT*4, stream);
  hipMemsetAsync(histU, 0, (size_t)N_USR*4, stream);
  hipMemcpyAsync(ent_res, entity_emb, (size_t)N_ENT*CH*4, hipMemcpyDeviceToDevice, stream);
  hipMemcpyAsync(usr_res, user_emb,   (size_t)N_USR*CH*4, hipMemcpyDeviceToDevice, stream);
  hipMemcpyAsync(cur_ent, entity_emb, (size_t)N_ENT*CH*4, hipMemcpyDeviceToDevice, stream);
  hipMemcpyAsync(cur_usr, user_emb,   (size_t)N_USR*CH*4, hipMemcpyDeviceToDevice, stream);

  // counting sorts with fused payload gather (edges by head, inter by row)
  k_hist<<<1024,256,0,stream>>>(head, N_EDGEC, histE);
  k_hist<<<512,256,0,stream>>>(irows, NNZC, histU);
  k_scan<<<1,1024,0,stream>>>(histE, startE, cursorE, N_ENT);
  k_scan<<<1,1024,0,stream>>>(histU, startU, cursorU, N_USR);
  k_scatter_sortE<<<1024,256,0,stream>>>(head, tail, edge_type, N_EDGEC, cursorE, trS);
  k_scatter_sortU<<<512,256,0,stream>>>(irows, icols, inter_vals, NNZC, cursorU, icolsS, ivalsS);

  dim3 gg(N_ENT/128, N_ENT/128);

  // build_adj #1 on original entity_emb (sim matrix staged in the adj output region)
  k_split<<<N_ENT/4,256,0,stream>>>(entity_emb, abufA, abufB);
  k_gemm_bf16<<<gg,256,0,stream>>>(abufA, abufB, adj);
  k_topk<<<N_ENT,64,0,stream>>>(adj, knn_idx0, knn_val0, rowsum0);

  // 2 hops
  for(int hop=0; hop<2; ++hop){
    k_q<<<N_ENT/4,256,0,stream>>>(cur_ent, W, q);
    k_edge_agg<<<N_ENT/4,256,0,stream>>>(trS, startE, cur_ent, W, q, wbuf, agg);
    k_user<<<N_USR/4,256,0,stream>>>(icolsS, ivalsS, startU, cur_ent, W, cur_usr, usr_res);
    k_entfin<<<N_ENT/4,256,0,stream>>>(agg, cur_ent, ent_res);
  }

  // build_adj #2 on entity_res_emb
  k_split<<<N_ENT/4,256,0,stream>>>(ent_res, abufA, abufB);
  k_gemm_bf16<<<gg,256,0,stream>>>(abufA, abufB, adj);
  k_topk<<<N_ENT,64,0,stream>>>(adj, knn_idx1, knn_val1, rowsum1);

  // item_adj = 0.5*new + 0.5*origin, single-pass dense write (no memset, no atomics)
  k_write_adj<<<N_ENT,256,0,stream>>>(knn_idx0, knn_val0, rowsum0,
                                      knn_idx1, knn_val1, rowsum1, adj);
}

// Round 9
// 847.144 us; speedup vs baseline: 1.2592x; 1.1802x over previous
//
#include <hip/hip_runtime.h>
#include <hip/hip_bf16.h>

#define N_ENT   8192
#define N_USR   16384
#define CH      64
#define N_EDGEC 1000000
#define NNZC    500000
#define TOPKC   10
#define NRELM1  8
#define KSPLIT  384   // 6 limb-blocks of 64: A=[h,h,m,l,h,m], B=[h,m,h,h,l,m]
#define BKS     96    // K-step (4 steps of 96)
#define NTILE   64    // column tiles per row (8192/128)

typedef __bf16 bf16x8 __attribute__((ext_vector_type(8)));
typedef float  f32x4  __attribute__((ext_vector_type(4)));

static __device__ __forceinline__ float waveReduceSum(float v){
#pragma unroll
  for(int o=1;o<64;o<<=1) v += __shfl_xor(v,o,64);
  return v;
}
static __device__ __forceinline__ float waveReduceMax(float v){
#pragma unroll
  for(int o=1;o<64;o<<=1) v = fmaxf(v, __shfl_xor(v,o,64));
  return v;
}
static __device__ __forceinline__ unsigned long long u64max(unsigned long long a, unsigned long long b){
  return a>b? a: b;
}
static __device__ __forceinline__ unsigned mapf(float v){
  unsigned u = __float_as_uint(v);
  return (u & 0x80000000u) ? ~u : (u | 0x80000000u);
}
static __device__ __forceinline__ float unmapf(unsigned mk){
  unsigned uo = (mk & 0x80000000u) ? (mk ^ 0x80000000u) : ~mk;
  return __uint_as_float(uo);
}
// f32 -> bf16 RTN-even (inputs finite)
static __device__ __forceinline__ ushort f2bf(float x){
  unsigned u = __float_as_uint(x);
  return (ushort)((u + 0x7FFFu + ((u>>16)&1u)) >> 16);
}
static __device__ __forceinline__ float bf2f(ushort h){
  return __uint_as_float((unsigned)h<<16);
}

// ---------------- sorting (counting sort by segment key) ----------------
__global__ void k_hist(const int* __restrict__ keys, int n, int* __restrict__ hist){
  int i = blockIdx.x*blockDim.x + threadIdx.x;
  int stride = gridDim.x*blockDim.x;
  for(; i<n; i+=stride) atomicAdd(&hist[keys[i]], 1);
}

__global__ __launch_bounds__(1024) void k_scan(const int* __restrict__ hist,
                                               int* __restrict__ start,
                                               int* __restrict__ cursor, int n){
  __shared__ int part[1024];
  int t = threadIdx.x;
  int chunk = n/1024;
  int base = t*chunk;
  int s = 0;
  for(int i=0;i<chunk;i++) s += hist[base+i];
  part[t] = s; __syncthreads();
  for(int off=1; off<1024; off<<=1){
    int v = (t>=off) ? part[t-off] : 0;
    __syncthreads();
    part[t] += v;
    __syncthreads();
  }
  int run = (t==0) ? 0 : part[t-1];
  for(int i=0;i<chunk;i++){
    start[base+i] = run; cursor[base+i] = run;
    run += hist[base+i];
  }
  if(t==1023) start[n] = run;
}

__global__ void k_scatter_sortE(const int* __restrict__ head,
                                const int* __restrict__ tail,
                                const int* __restrict__ etype, int n,
                                int* __restrict__ cursor, int* __restrict__ trS){
  int i = blockIdx.x*blockDim.x + threadIdx.x;
  int stride = gridDim.x*blockDim.x;
  for(; i<n; i+=stride){
    int pos = atomicAdd(&cursor[head[i]], 1);
    trS[pos] = (tail[i] & 8191) | ((etype[i]-1)<<13);
  }
}

__global__ void k_scatter_sortU(const int* __restrict__ irows,
                                const int* __restrict__ icols,
                                const float* __restrict__ ivals, int n,
                                int* __restrict__ cursor,
                                int* __restrict__ icolsS, float* __restrict__ ivalsS){
  int i = blockIdx.x*blockDim.x + threadIdx.x;
  int stride = gridDim.x*blockDim.x;
  for(; i<n; i+=stride){
    int pos = atomicAdd(&cursor[irows[i]], 1);
    icolsS[pos] = icols[i];
    ivalsS[pos] = ivals[i];
  }
}

// ---------------- normalize + triple-bf16 split into A/B limb layouts ----------------
__global__ __launch_bounds__(256) void k_split(const float* __restrict__ in,
                                               ushort* __restrict__ outA,
                                               ushort* __restrict__ outB){
  int wave = threadIdx.x>>6, lane = threadIdx.x&63;
  int r = blockIdx.x*4 + wave;
  float v = in[(size_t)r*CH+lane];
  float ss = waveReduceSum(v*v);
  float x = v / sqrtf(ss);
  ushort h = f2bf(x);
  float r1 = x - bf2f(h);
  ushort m = f2bf(r1);
  float r2 = r1 - bf2f(m);
  ushort l = f2bf(r2);
  ushort* oA = outA + (size_t)r*KSPLIT;
  ushort* oB = outB + (size_t)r*KSPLIT;
  oA[lane]     =h; oA[64+lane] =h; oA[128+lane]=m;
  oA[192+lane] =l; oA[256+lane]=h; oA[320+lane]=m;
  oB[lane]     =h; oB[64+lane] =m; oB[128+lane]=h;
  oB[192+lane] =h; oB[256+lane]=l; oB[320+lane]=m;
}

// ---------------- sim GEMM + fused per-row tile-max epilogue ----------------
__global__ __launch_bounds__(256) void k_gemm_bf16(const ushort* __restrict__ A,
                                                   const ushort* __restrict__ B,
                                                   float* __restrict__ C,
                                                   float* __restrict__ rowmax){
  __shared__ ushort As[128*BKS];
  __shared__ ushort Bs[128*BKS];
  const int tid = threadIdx.x, lane = tid&63, wid = tid>>6;
  const int bi = blockIdx.y*128, bj = blockIdx.x*128;
  const int wr = (wid>>1)*64, wc = (wid&1)*64;
  const int r16 = lane&15, kg = lane>>4;

  f32x4 acc[4][4] = {};

  const uint4* gA = (const uint4*)A + (size_t)bi*(KSPLIT/8);
  const uint4* gB = (const uint4*)B + (size_t)bj*(KSPLIT/8);
  const int row2 = tid>>1, half = tid&1;

  for(int s=0; s<KSPLIT/BKS; ++s){
    __syncthreads();
#pragma unroll
    for(int jj=0;jj<6;jj++){
      *(uint4*)&As[row2*BKS + half*48 + jj*8] = gA[row2*(KSPLIT/8) + s*12 + half*6 + jj];
      *(uint4*)&Bs[row2*BKS + half*48 + jj*8] = gB[row2*(KSPLIT/8) + s*12 + half*6 + jj];
    }
    __syncthreads();
#pragma unroll
    for(int kk=0;kk<3;kk++){
      bf16x8 a[4], b[4];
#pragma unroll
      for(int m=0;m<4;m++)
        a[m] = *(const bf16x8*)&As[(wr+m*16+r16)*BKS + kk*32 + kg*8];
#pragma unroll
      for(int n=0;n<4;n++)
        b[n] = *(const bf16x8*)&Bs[(wc+n*16+r16)*BKS + kk*32 + kg*8];
#pragma unroll
      for(int m=0;m<4;m++)
#pragma unroll
        for(int n=0;n<4;n++)
          acc[m][n] = __builtin_amdgcn_mfma_f32_16x16x32_bf16(a[m], b[n], acc[m][n], 0,0,0);
    }
  }

  // C/D layout: col = lane&15, row = (lane>>4)*4 + reg  (m89-verified)
#pragma unroll
  for(int m=0;m<4;m++){
#pragma unroll
    for(int n=0;n<4;n++){
      size_t base = (size_t)(bi + wr + m*16 + kg*4)*N_ENT + (bj + wc + n*16 + r16);
      C[base]          = acc[m][n][0];
      C[base+N_ENT]    = acc[m][n][1];
      C[base+2*N_ENT]  = acc[m][n][2];
      C[base+3*N_ENT]  = acc[m][n][3];
    }
  }

  // ---- fused epilogue: per-row max of this 128-col tile ----
  // per-lane: max over n and reg-local rows, then reduce across the 16 r16 lanes
  float tmax[4][4];   // [m][reg]
#pragma unroll
  for(int m=0;m<4;m++){
#pragma unroll
    for(int rg=0;rg<4;rg++){
      float v = acc[m][0][rg];
      v = fmaxf(v, acc[m][1][rg]);
      v = fmaxf(v, acc[m][2][rg]);
      v = fmaxf(v, acc[m][3][rg]);
#pragma unroll
      for(int o=1;o<16;o<<=1) v = fmaxf(v, __shfl_xor(v, o, 64));
      tmax[m][rg] = v;   // valid on all lanes of the 16-lane group
    }
  }
  __syncthreads();                 // As/Bs dead; reuse As as f32 scratch
  float* rm = (float*)As;
  if(((wid&1)==0) && r16==0){
#pragma unroll
    for(int m=0;m<4;m++)
#pragma unroll
      for(int rg=0;rg<4;rg++)
        rm[wr + m*16 + kg*4 + rg] = tmax[m][rg];
  }
  __syncthreads();
  if(((wid&1)==1) && r16==0){
#pragma unroll
    for(int m=0;m<4;m++)
#pragma unroll
      for(int rg=0;rg<4;rg++){
        int rrow = wr + m*16 + kg*4 + rg;
        rowmax[(size_t)(bi+rrow)*NTILE + blockIdx.x] = fmaxf(tmax[m][rg], rm[rrow]);
      }
  }
}

// ---------------- per-row top-k via tile-max pruning, one wave per row ----------------
// tau = 10th-largest tile max  =>  all top-10 elements >= tau and live in tiles
// whose max >= tau. Exact (val, -col) selection over the candidate superset.
#define CANDCAP 256
__global__ __launch_bounds__(64) void k_topk(const float* __restrict__ S,
                                             const float* __restrict__ rowmax,
                                             int* __restrict__ knn_idx,
                                             float* __restrict__ knn_val,
                                             float* __restrict__ rowsum){
  const int row = blockIdx.x;
  const int lane = threadIdx.x;
  const float4* s4 = (const float4*)(S + (size_t)row*N_ENT);

  __shared__ unsigned long long cand[CANDCAP];
  __shared__ int tlist[NTILE];
  __shared__ int cnt, tcnt;
  if(lane==0){ cnt=0; tcnt=0; }
  __syncthreads();

  // exact 10th-largest tile max (lane id breaks ties -> unique removal)
  float tm = rowmax[(size_t)row*NTILE + lane];
  unsigned long long work = ((unsigned long long)mapf(tm)<<32) | (unsigned)lane;
  unsigned long long w = 0;
  for(int sel=0; sel<TOPKC; ++sel){
    w = work;
#pragma unroll
    for(int o=1;o<64;o<<=1) w = u64max(w, __shfl_xor(w,o,64));
    if(work == w) work = 0ull;
  }
  float tauf = unmapf((unsigned)(w>>32));

  if(tm >= tauf){ int p = atomicAdd(&tcnt,1); tlist[p] = lane; }
  __syncthreads();
  int nt = tcnt;

  // scan qualifying tiles, 2 tiles per iteration (32 lanes each)
  for(int i = (lane>>5); i < nt; i += 2){
    int t  = tlist[i];
    int fo = lane&31;
    float4 v = s4[t*32 + fo];
    int c0 = t*128 + fo*4;
    float vv[4] = {v.x,v.y,v.z,v.w};
#pragma unroll
    for(int j=0;j<4;j++){
      if(vv[j] >= tauf){
        int pos = atomicAdd(&cnt,1);
        if(pos < CANDCAP)
          cand[pos] = ((unsigned long long)mapf(vv[j])<<32)
                    | (unsigned long long)(0xFFFFFFFFu - (unsigned)(c0+j));
      }
    }
  }
  __syncthreads();
  int n = cnt;

  if(n <= CANDCAP){
    unsigned long long c0 = (lane      < n) ? cand[lane]       : 0ull;
    unsigned long long c1 = (lane+64   < n) ? cand[lane+64]    : 0ull;
    unsigned long long c2 = (lane+128  < n) ? cand[lane+128]   : 0ull;
    unsigned long long c3 = (lane+192  < n) ? cand[lane+192]   : 0ull;
    float rs = 0.f;
    for(int sel=0; sel<TOPKC; ++sel){
      unsigned long long m = u64max(u64max(c0,c1), u64max(c2,c3));
#pragma unroll
      for(int o=1;o<64;o<<=1) m = u64max(m, __shfl_xor(m,o,64));
      if(c0==m) c0=0ull; else if(c1==m) c1=0ull;
      else if(c2==m) c2=0ull; else if(c3==m) c3=0ull;
      if(lane==0){
        float v = unmapf((unsigned)(m>>32));
        int col = (int)(0xFFFFFFFFu - (unsigned)(m & 0xFFFFFFFFu));
        knn_idx[row*TOPKC+sel] = col;
        knn_val[row*TOPKC+sel] = v;
        rs += v;
      }
    }
    if(lane==0) rowsum[row] = rs;
  } else {
    // pathological fallback: exact register insertion scan over the full row
    unsigned long long loc[TOPKC];
#pragma unroll
    for(int i=0;i<TOPKC;i++) loc[i]=0ull;
    for(int it=0; it<N_ENT/256; ++it){
      int vi = it*64+lane;
      float4 v = s4[vi];
      int c0i = vi*4;
      float vv[4] = {v.x,v.y,v.z,v.w};
#pragma unroll
      for(int j=0;j<4;j++){
        unsigned u = mapf(vv[j]);
        unsigned long long key = ((unsigned long long)u<<32)
                               | (unsigned long long)(0xFFFFFFFFu - (unsigned)(c0i+j));
        if(key > loc[TOPKC-1]){
          unsigned long long t = key;
#pragma unroll
          for(int z=0; z<TOPKC; ++z){
            if(t > loc[z]){ unsigned long long tmp=loc[z]; loc[z]=t; t=tmp; }
          }
        }
      }
    }
    float rs = 0.f;
    for(int sel=0; sel<TOPKC; ++sel){
      unsigned long long m = loc[0];
#pragma unroll
      for(int o=1;o<64;o<<=1) m = u64max(m, __shfl_xor(m,o,64));
      if(loc[0] == m){
#pragma unroll
        for(int z=0;z<TOPKC-1;++z) loc[z]=loc[z+1];
        loc[TOPKC-1]=0ull;
      }
      if(lane==0){
        float v = unmapf((unsigned)(m>>32));
        int col = (int)(0xFFFFFFFFu - (unsigned)(m & 0xFFFFFFFFu));
        knn_idx[row*TOPKC+sel] = col;
        knn_val[row*TOPKC+sel] = v;
        rs += v;
      }
    }
    if(lane==0) rowsum[row] = rs;
  }
}

// ---------------- q[i][r] = ||ent_i * W_r||^2 ----------------
__global__ __launch_bounds__(256) void k_q(const float* __restrict__ ent,
                                           const float* __restrict__ W,
                                           float* __restrict__ q){
  int wave=threadIdx.x>>6, lane=threadIdx.x&63;
  int r = blockIdx.x*4+wave;
  if(r>=N_ENT) return;
  float x = ent[(size_t)r*CH+lane];
#pragma unroll
  for(int rel=0; rel<NRELM1; rel++){
    float tt = x*W[rel*CH+lane];
    float s = waveReduceSum(tt*tt);
    if(lane==0) q[r*NRELM1+rel]=s;
  }
}

// ---------------- per-head edge aggregation (contiguous sorted arrays) ----------------
__global__ __launch_bounds__(256) void k_edge_agg(
    const int* __restrict__ trS, const int* __restrict__ startE,
    const float* __restrict__ ent, const float* __restrict__ W,
    const float* __restrict__ q, float* __restrict__ wbuf,
    float* __restrict__ agg){
  int wave=threadIdx.x>>6, lane=threadIdx.x&63;
  int h = blockIdx.x*4+wave;
  if(h>=N_ENT) return;
  int s = startE[h], e2 = startE[h+1];

  float qh[NRELM1];
#pragma unroll
  for(int r=0;r<NRELM1;r++) qh[r] = q[h*NRELM1+r];

  float mx = 0.f;
  for(int p=s+lane; p<e2; p+=64){
    int tr = trS[p];
    int tl = tr & 8191, r = tr>>13;
    float att = qh[r]*q[tl*NRELM1+r];
    wbuf[p] = att;
    mx = fmaxf(mx, att);
  }
  mx = waveReduceMax(mx);

  float dn = 0.f;
  for(int p=s+lane; p<e2; p+=64){
    float e = expf(wbuf[p]-mx);
    wbuf[p] = e;
    dn += e;
  }
  dn = waveReduceSum(dn);
  float inv = (dn>0.f) ? 1.f/dn : 0.f;

  float wr[NRELM1];
#pragma unroll
  for(int r=0;r<NRELM1;r++) wr[r] = W[r*CH+lane];
  float acc = 0.f;
  for(int p=s; p<e2; p++){
    int tr = trS[p];
    int tl = tr & 8191, r = tr>>13;
    float wgt = wbuf[p]*inv;
    acc = fmaf(wgt*wr[r], ent[(size_t)tl*CH+lane], acc);
  }
  agg[(size_t)h*CH+lane] = acc;
}

// ---------------- per-user: sparse agg + gated score + l2norm + residual ----------------
__global__ __launch_bounds__(256) void k_user(
    const int* __restrict__ icolsS, const float* __restrict__ ivalsS,
    const int* __restrict__ startU,
    const float* __restrict__ ent, const float* __restrict__ W,
    float* __restrict__ usr, float* __restrict__ usr_res){
  int wave=threadIdx.x>>6, lane=threadIdx.x&63;
  int u = blockIdx.x*4+wave;
  if(u>=N_USR) return;
  float ue = usr[(size_t)u*CH+lane];
  float l[NRELM1];
#pragma unroll
  for(int r=0;r<NRELM1;r++) l[r] = waveReduceSum(ue*W[r*CH+lane]);
  float lm = l[0];
#pragma unroll
  for(int r=1;r<NRELM1;r++) lm = fmaxf(lm,l[r]);
  float se=0.f;
#pragma unroll
  for(int r=0;r<NRELM1;r++){ l[r]=expf(l[r]-lm); se+=l[r]; }
  float inv = 1.f/se;
  float g = 0.f;
#pragma unroll
  for(int r=0;r<NRELM1;r++) g = fmaf(l[r]*inv, W[r*CH+lane], g);
  float acc=0.f;
  int s=startU[u], e2=startU[u+1];
  for(int p=s;p<e2;p++){
    acc = fmaf(ivalsS[p], ent[(size_t)icolsS[p]*CH+lane], acc);
  }
  float res = acc*(1.f+g);
  float nrm = sqrtf(waveReduceSum(res*res));
  float outv = res / fmaxf(nrm, 1e-12f);
  usr_res[(size_t)u*CH+lane] += outv;
  usr[(size_t)u*CH+lane] = outv;
}

// ---------------- entity finalize: l2norm + residual ----------------
__global__ __launch_bounds__(256) void k_entfin(const float* __restrict__ agg,
                                                float* __restrict__ cur,
                                                float* __restrict__ res){
  int wave=threadIdx.x>>6, lane=threadIdx.x&63;
  int r = blockIdx.x*4+wave;
  if(r>=N_ENT) return;
  float v = agg[(size_t)r*CH+lane];
  float nrm = sqrtf(waveReduceSum(v*v));
  float outv = v / fmaxf(nrm, 1e-12f);
  cur[(size_t)r*CH+lane]=outv;
  res[(size_t)r*CH+lane]+=outv;
}

// ---------------- fused adj writer: coalesced zeros, then direct patch ----------------
__global__ __launch_bounds__(256) void k_write_adj(
    const int* __restrict__ ki0, const float* __restrict__ kv0,
    const float* __restrict__ rs0,
    const int* __restrict__ ki1, const float* __restrict__ kv1,
    const float* __restrict__ rs1,
    float* __restrict__ adj){
  const int row = blockIdx.x;
  const int t = threadIdx.x;
  __shared__ int   cols[2*TOPKC];
  __shared__ float vals[2*TOPKC];

  if(t < TOPKC){
    int c = ki1[row*TOPKC+t];
    cols[t] = c;
    vals[t] = 0.5f * kv1[row*TOPKC+t] / (sqrtf(rs1[row]) * sqrtf(rs1[c]));
  } else if(t < 2*TOPKC){
    int i = t - TOPKC;
    int c = ki0[row*TOPKC+i];
    cols[t] = c;
    vals[t] = 0.5f * kv0[row*TOPKC+i] / (sqrtf(rs0[row]) * sqrtf(rs0[c]));
  }
  __syncthreads();
  if(t==0){
    for(int i=TOPKC;i<2*TOPKC;i++){
      int c = cols[i];
      for(int j=0;j<TOPKC;j++){
        if(cols[j]==c){ vals[j]+=vals[i]; cols[i]=-1; break; }
      }
    }
  }
  __syncthreads();

  float4* adj4 = (float4*)(adj + (size_t)row*N_ENT);
  float4 z = {0.f,0.f,0.f,0.f};
#pragma unroll
  for(int k=0;k<8;k++) adj4[k*256 + t] = z;
  __syncthreads();
  if(t < 2*TOPKC){
    int c = cols[t];
    if(c >= 0) adj[(size_t)row*N_ENT + c] = vals[t];
  }
}

extern "C" void kernel_launch(void* const* d_in, const int* in_sizes, int n_in,
                              void* d_out, int out_size, void* d_ws, size_t ws_size,
                              hipStream_t stream){
  const float* user_emb   = (const float*)d_in[0];
  const float* entity_emb = (const float*)d_in[1];
  const int*   edge_index = (const int*)d_in[2];
  const int*   edge_type  = (const int*)d_in[3];
  const int*   inter_idx  = (const int*)d_in[4];
  const float* inter_vals = (const float*)d_in[5];
  const float* W          = (const float*)d_in[6];

  const int* head  = edge_index;
  const int* tail  = edge_index + N_EDGEC;
  const int* irows = inter_idx;
  const int* icols = inter_idx + NNZC;

  float* out     = (float*)d_out;
  float* ent_res = out;
  float* usr_res = out + (size_t)N_ENT*CH;
  float* adj     = out + (size_t)N_ENT*CH + (size_t)N_USR*CH;

  char* wp = (char*)d_ws;
  auto alloc = [&](size_t bytes)->void*{
    void* p = (void*)wp; wp += (bytes+255)/256*256; return p;
  };
  ushort* abufA  = (ushort*)alloc((size_t)N_ENT*KSPLIT*2);
  ushort* abufB  = (ushort*)alloc((size_t)N_ENT*KSPLIT*2);
  float* rowmax  = (float*)alloc((size_t)N_ENT*NTILE*4);
  float* cur_ent = (float*)alloc((size_t)N_ENT*CH*4);
  float* cur_usr = (float*)alloc((size_t)N_USR*CH*4);
  float* agg     = (float*)alloc((size_t)N_ENT*CH*4);
  float* q       = (float*)alloc((size_t)N_ENT*NRELM1*4);
  int*   histE   = (int*)alloc((size_t)N_ENT*4);
  int*   startE  = (int*)alloc((size_t)(N_ENT+1)*4);
  int*   cursorE = (int*)alloc((size_t)N_ENT*4);
  int*   trS     = (int*)alloc((size_t)N_EDGEC*4);
  int*   histU   = (int*)alloc((size_t)N_USR*4);
  int*   startU  = (int*)alloc((size_t)(N_USR+1)*4);
  int*   cursorU = (int*)alloc((size_t)N_USR*4);
  int*   icolsS  = (int*)alloc((size_t)NNZC*4);
  float* ivalsS  = (float*)alloc((size_t)NNZC*4);
  int*   knn_idx0= (int*)alloc((size_t)N_ENT*TOPKC*4);
  float* knn_val0= (float*)alloc((size_t)N_ENT*TOPKC*4);
  float* rowsum0 = (float*)alloc((size_t)N_ENT*4);
  int*   knn_idx1= (int*)alloc((size_t)N_ENT*TOPKC*4);
  float* knn_val1= (float*)alloc((size_t)N_ENT*TOPKC*4);
  float* rowsum1 = (float*)alloc((size_t)N_ENT*4);

  // wbuf for edge softmax lives in the adj output region (256MB, idle during hops)
  float* wbuf = adj;

  // init
  hipMemsetAsync(histE, 0, (size_t)N_ENT*4, stream);
  hipMemsetAsync(histU, 0, (size_t)N_USR*4, stream);
  hipMemcpyAsync(ent_res, entity_emb, (size_t)N_ENT*CH*4, hipMemcpyDeviceToDevice, stream);
  hipMemcpyAsync(usr_res, user_emb,   (size_t)N_USR*CH*4, hipMemcpyDeviceToDevice, stream);
  hipMemcpyAsync(cur_ent, entity_emb, (size_t)N_ENT*CH*4, hipMemcpyDeviceToDevice, stream);
  hipMemcpyAsync(cur_usr, user_emb,   (size_t)N_USR*CH*4, hipMemcpyDeviceToDevice, stream);

  // counting sorts with fused payload gather (edges by head, inter by row)
  k_hist<<<1024,256,0,stream>>>(head, N_EDGEC, histE);
  k_hist<<<512,256,0,stream>>>(irows, NNZC, histU);
  k_scan<<<1,1024,0,stream>>>(histE, startE, cursorE, N_ENT);
  k_scan<<<1,1024,0,stream>>>(histU, startU, cursorU, N_USR);
  k_scatter_sortE<<<1024,256,0,stream>>>(head, tail, edge_type, N_EDGEC, cursorE, trS);
  k_scatter_sortU<<<512,256,0,stream>>>(irows, icols, inter_vals, NNZC, cursorU, icolsS, ivalsS);

  dim3 gg(N_ENT/128, N_ENT/128);

  // build_adj #1 on original entity_emb (sim matrix staged in the adj output region)
  k_split<<<N_ENT/4,256,0,stream>>>(entity_emb, abufA, abufB);
  k_gemm_bf16<<<gg,256,0,stream>>>(abufA, abufB, adj, rowmax);
  k_topk<<<N_ENT,64,0,stream>>>(adj, rowmax, knn_idx0, knn_val0, rowsum0);

  // 2 hops
  for(int hop=0; hop<2; ++hop){
    k_q<<<N_ENT/4,256,0,stream>>>(cur_ent, W, q);
    k_edge_agg<<<N_ENT/4,256,0,stream>>>(trS, startE, cur_ent, W, q, wbuf, agg);
    k_user<<<N_USR/4,256,0,stream>>>(icolsS, ivalsS, startU, cur_ent, W, cur_usr, usr_res);
    k_entfin<<<N_ENT/4,256,0,stream>>>(agg, cur_ent, ent_res);
  }

  // build_adj #2 on entity_res_emb
  k_split<<<N_ENT/4,256,0,stream>>>(ent_res, abufA, abufB);
  k_gemm_bf16<<<gg,256,0,stream>>>(abufA, abufB, adj, rowmax);
  k_topk<<<N_ENT,64,0,stream>>>(adj, rowmax, knn_idx1, knn_val1, rowsum1);

  // item_adj = 0.5*new + 0.5*origin, single-pass dense write (no memset, no atomics)
  k_write_adj<<<N_ENT,256,0,stream>>>(knn_idx0, knn_val0, rowsum0,
                                      knn_idx1, knn_val1, rowsum1, adj);
}

// Round 10
// 839.319 us; speedup vs baseline: 1.2709x; 1.0093x over previous
//
#include <hip/hip_runtime.h>
#include <hip/hip_bf16.h>

#define N_ENT   8192
#define N_USR   16384
#define CH      64
#define N_EDGEC 1000000
#define NNZC    500000
#define TOPKC   10
#define NRELM1  8
#define KSPLIT  384   // 6 limb-blocks of 64: A=[h,h,m,l,h,m], B=[h,m,h,h,l,m]
#define BKS     96    // K-step (4 steps of 96)
#define LDSP    104   // padded LDS row stride (208B = 52 dwords -> conflict-free b128 reads)
#define NTILE   64    // column tiles per row (8192/128)

typedef __bf16 bf16x8 __attribute__((ext_vector_type(8)));
typedef float  f32x4  __attribute__((ext_vector_type(4)));

static __device__ __forceinline__ float waveReduceSum(float v){
#pragma unroll
  for(int o=1;o<64;o<<=1) v += __shfl_xor(v,o,64);
  return v;
}
static __device__ __forceinline__ float waveReduceMax(float v){
#pragma unroll
  for(int o=1;o<64;o<<=1) v = fmaxf(v, __shfl_xor(v,o,64));
  return v;
}
static __device__ __forceinline__ unsigned long long u64max(unsigned long long a, unsigned long long b){
  return a>b? a: b;
}
static __device__ __forceinline__ unsigned mapf(float v){
  unsigned u = __float_as_uint(v);
  return (u & 0x80000000u) ? ~u : (u | 0x80000000u);
}
static __device__ __forceinline__ float unmapf(unsigned mk){
  unsigned uo = (mk & 0x80000000u) ? (mk ^ 0x80000000u) : ~mk;
  return __uint_as_float(uo);
}
// f32 -> bf16 RTN-even (inputs finite)
static __device__ __forceinline__ ushort f2bf(float x){
  unsigned u = __float_as_uint(x);
  return (ushort)((u + 0x7FFFu + ((u>>16)&1u)) >> 16);
}
static __device__ __forceinline__ float bf2f(ushort h){
  return __uint_as_float((unsigned)h<<16);
}

// ---------------- sorting (counting sort by segment key) ----------------
__global__ void k_hist(const int* __restrict__ keys, int n, int* __restrict__ hist){
  int i = blockIdx.x*blockDim.x + threadIdx.x;
  int stride = gridDim.x*blockDim.x;
  for(; i<n; i+=stride) atomicAdd(&hist[keys[i]], 1);
}

__global__ __launch_bounds__(1024) void k_scan(const int* __restrict__ hist,
                                               int* __restrict__ start,
                                               int* __restrict__ cursor, int n){
  __shared__ int part[1024];
  int t = threadIdx.x;
  int chunk = n/1024;
  int base = t*chunk;
  int s = 0;
  for(int i=0;i<chunk;i++) s += hist[base+i];
  part[t] = s; __syncthreads();
  for(int off=1; off<1024; off<<=1){
    int v = (t>=off) ? part[t-off] : 0;
    __syncthreads();
    part[t] += v;
    __syncthreads();
  }
  int run = (t==0) ? 0 : part[t-1];
  for(int i=0;i<chunk;i++){
    start[base+i] = run; cursor[base+i] = run;
    run += hist[base+i];
  }
  if(t==1023) start[n] = run;
}

__global__ void k_scatter_sortE(const int* __restrict__ head,
                                const int* __restrict__ tail,
                                const int* __restrict__ etype, int n,
                                int* __restrict__ cursor, int* __restrict__ trS){
  int i = blockIdx.x*blockDim.x + threadIdx.x;
  int stride = gridDim.x*blockDim.x;
  for(; i<n; i+=stride){
    int pos = atomicAdd(&cursor[head[i]], 1);
    trS[pos] = (tail[i] & 8191) | ((etype[i]-1)<<13);
  }
}

__global__ void k_scatter_sortU(const int* __restrict__ irows,
                                const int* __restrict__ icols,
                                const float* __restrict__ ivals, int n,
                                int* __restrict__ cursor,
                                int* __restrict__ icolsS, float* __restrict__ ivalsS){
  int i = blockIdx.x*blockDim.x + threadIdx.x;
  int stride = gridDim.x*blockDim.x;
  for(; i<n; i+=stride){
    int pos = atomicAdd(&cursor[irows[i]], 1);
    icolsS[pos] = icols[i];
    ivalsS[pos] = ivals[i];
  }
}

// ---------------- normalize + triple-bf16 split into A/B limb layouts ----------------
__global__ __launch_bounds__(256) void k_split(const float* __restrict__ in,
                                               ushort* __restrict__ outA,
                                               ushort* __restrict__ outB){
  int wave = threadIdx.x>>6, lane = threadIdx.x&63;
  int r = blockIdx.x*4 + wave;
  float v = in[(size_t)r*CH+lane];
  float ss = waveReduceSum(v*v);
  float x = v / sqrtf(ss);
  ushort h = f2bf(x);
  float r1 = x - bf2f(h);
  ushort m = f2bf(r1);
  float r2 = r1 - bf2f(m);
  ushort l = f2bf(r2);
  ushort* oA = outA + (size_t)r*KSPLIT;
  ushort* oB = outB + (size_t)r*KSPLIT;
  oA[lane]     =h; oA[64+lane] =h; oA[128+lane]=m;
  oA[192+lane] =l; oA[256+lane]=h; oA[320+lane]=m;
  oB[lane]     =h; oB[64+lane] =m; oB[128+lane]=h;
  oB[192+lane] =h; oB[256+lane]=l; oB[320+lane]=m;
}

// ---------------- sim GEMM + fused per-row tile-max epilogue ----------------
__global__ __launch_bounds__(256) void k_gemm_bf16(const ushort* __restrict__ A,
                                                   const ushort* __restrict__ B,
                                                   float* __restrict__ C,
                                                   float* __restrict__ rowmax){
  __shared__ ushort As[128*LDSP];
  __shared__ ushort Bs[128*LDSP];
  const int tid = threadIdx.x, lane = tid&63, wid = tid>>6;
  const int bi = blockIdx.y*128, bj = blockIdx.x*128;
  const int wr = (wid>>1)*64, wc = (wid&1)*64;
  const int r16 = lane&15, kg = lane>>4;

  f32x4 acc[4][4] = {};

  const uint4* gA = (const uint4*)A + (size_t)bi*(KSPLIT/8);
  const uint4* gB = (const uint4*)B + (size_t)bj*(KSPLIT/8);
  const int row2 = tid>>1, half = tid&1;

  for(int s=0; s<KSPLIT/BKS; ++s){
    __syncthreads();
#pragma unroll
    for(int jj=0;jj<6;jj++){
      *(uint4*)&As[row2*LDSP + half*48 + jj*8] = gA[row2*(KSPLIT/8) + s*12 + half*6 + jj];
      *(uint4*)&Bs[row2*LDSP + half*48 + jj*8] = gB[row2*(KSPLIT/8) + s*12 + half*6 + jj];
    }
    __syncthreads();
#pragma unroll
    for(int kk=0;kk<3;kk++){
      bf16x8 a[4], b[4];
#pragma unroll
      for(int m=0;m<4;m++)
        a[m] = *(const bf16x8*)&As[(wr+m*16+r16)*LDSP + kk*32 + kg*8];
#pragma unroll
      for(int n=0;n<4;n++)
        b[n] = *(const bf16x8*)&Bs[(wc+n*16+r16)*LDSP + kk*32 + kg*8];
#pragma unroll
      for(int m=0;m<4;m++)
#pragma unroll
        for(int n=0;n<4;n++)
          acc[m][n] = __builtin_amdgcn_mfma_f32_16x16x32_bf16(a[m], b[n], acc[m][n], 0,0,0);
    }
  }

  // C/D layout: col = lane&15, row = (lane>>4)*4 + reg  (m89-verified)
#pragma unroll
  for(int m=0;m<4;m++){
#pragma unroll
    for(int n=0;n<4;n++){
      size_t base = (size_t)(bi + wr + m*16 + kg*4)*N_ENT + (bj + wc + n*16 + r16);
      C[base]          = acc[m][n][0];
      C[base+N_ENT]    = acc[m][n][1];
      C[base+2*N_ENT]  = acc[m][n][2];
      C[base+3*N_ENT]  = acc[m][n][3];
    }
  }

  // ---- fused epilogue: per-row max of this 128-col tile ----
  float tmax[4][4];   // [m][reg]
#pragma unroll
  for(int m=0;m<4;m++){
#pragma unroll
    for(int rg=0;rg<4;rg++){
      float v = acc[m][0][rg];
      v = fmaxf(v, acc[m][1][rg]);
      v = fmaxf(v, acc[m][2][rg]);
      v = fmaxf(v, acc[m][3][rg]);
#pragma unroll
      for(int o=1;o<16;o<<=1) v = fmaxf(v, __shfl_xor(v, o, 64));
      tmax[m][rg] = v;
    }
  }
  __syncthreads();                 // As/Bs dead; reuse As as f32 scratch
  float* rm = (float*)As;
  if(((wid&1)==0) && r16==0){
#pragma unroll
    for(int m=0;m<4;m++)
#pragma unroll
      for(int rg=0;rg<4;rg++)
        rm[wr + m*16 + kg*4 + rg] = tmax[m][rg];
  }
  __syncthreads();
  if(((wid&1)==1) && r16==0){
#pragma unroll
    for(int m=0;m<4;m++)
#pragma unroll
      for(int rg=0;rg<4;rg++){
        int rrow = wr + m*16 + kg*4 + rg;
        rowmax[(size_t)(bi+rrow)*NTILE + blockIdx.x] = fmaxf(tmax[m][rg], rm[rrow]);
      }
  }
}

// ---------------- per-row top-k via tile-max pruning, one wave per row ----------------
#define CANDCAP 256
__global__ __launch_bounds__(64) void k_topk(const float* __restrict__ S,
                                             const float* __restrict__ rowmax,
                                             int* __restrict__ knn_idx,
                                             float* __restrict__ knn_val,
                                             float* __restrict__ rowsum){
  const int row = blockIdx.x;
  const int lane = threadIdx.x;
  const float4* s4 = (const float4*)(S + (size_t)row*N_ENT);

  __shared__ unsigned long long cand[CANDCAP];
  __shared__ int tlist[NTILE];
  __shared__ int cnt, tcnt;
  if(lane==0){ cnt=0; tcnt=0; }
  __syncthreads();

  // exact 10th-largest tile max (lane id breaks ties -> unique removal)
  float tm = rowmax[(size_t)row*NTILE + lane];
  unsigned long long work = ((unsigned long long)mapf(tm)<<32) | (unsigned)lane;
  unsigned long long w = 0;
  for(int sel=0; sel<TOPKC; ++sel){
    w = work;
#pragma unroll
    for(int o=1;o<64;o<<=1) w = u64max(w, __shfl_xor(w,o,64));
    if(work == w) work = 0ull;
  }
  float tauf = unmapf((unsigned)(w>>32));

  if(tm >= tauf){ int p = atomicAdd(&tcnt,1); tlist[p] = lane; }
  __syncthreads();
  int nt = tcnt;

  // scan qualifying tiles, 2 tiles per iteration (32 lanes each)
  for(int i = (lane>>5); i < nt; i += 2){
    int t  = tlist[i];
    int fo = lane&31;
    float4 v = s4[t*32 + fo];
    int c0 = t*128 + fo*4;
    float vv[4] = {v.x,v.y,v.z,v.w};
#pragma unroll
    for(int j=0;j<4;j++){
      if(vv[j] >= tauf){
        int pos = atomicAdd(&cnt,1);
        if(pos < CANDCAP)
          cand[pos] = ((unsigned long long)mapf(vv[j])<<32)
                    | (unsigned long long)(0xFFFFFFFFu - (unsigned)(c0+j));
      }
    }
  }
  __syncthreads();
  int n = cnt;

  if(n <= CANDCAP){
    unsigned long long c0 = (lane      < n) ? cand[lane]       : 0ull;
    unsigned long long c1 = (lane+64   < n) ? cand[lane+64]    : 0ull;
    unsigned long long c2 = (lane+128  < n) ? cand[lane+128]   : 0ull;
    unsigned long long c3 = (lane+192  < n) ? cand[lane+192]   : 0ull;
    float rs = 0.f;
    for(int sel=0; sel<TOPKC; ++sel){
      unsigned long long m = u64max(u64max(c0,c1), u64max(c2,c3));
#pragma unroll
      for(int o=1;o<64;o<<=1) m = u64max(m, __shfl_xor(m,o,64));
      if(c0==m) c0=0ull; else if(c1==m) c1=0ull;
      else if(c2==m) c2=0ull; else if(c3==m) c3=0ull;
      if(lane==0){
        float v = unmapf((unsigned)(m>>32));
        int col = (int)(0xFFFFFFFFu - (unsigned)(m & 0xFFFFFFFFu));
        knn_idx[row*TOPKC+sel] = col;
        knn_val[row*TOPKC+sel] = v;
        rs += v;
      }
    }
    if(lane==0) rowsum[row] = rs;
  } else {
    // pathological fallback: exact register insertion scan over the full row
    unsigned long long loc[TOPKC];
#pragma unroll
    for(int i=0;i<TOPKC;i++) loc[i]=0ull;
    for(int it=0; it<N_ENT/256; ++it){
      int vi = it*64+lane;
      float4 v = s4[vi];
      int c0i = vi*4;
      float vv[4] = {v.x,v.y,v.z,v.w};
#pragma unroll
      for(int j=0;j<4;j++){
        unsigned u = mapf(vv[j]);
        unsigned long long key = ((unsigned long long)u<<32)
                               | (unsigned long long)(0xFFFFFFFFu - (unsigned)(c0i+j));
        if(key > loc[TOPKC-1]){
          unsigned long long t = key;
#pragma unroll
          for(int z=0; z<TOPKC; ++z){
            if(t > loc[z]){ unsigned long long tmp=loc[z]; loc[z]=t; t=tmp; }
          }
        }
      }
    }
    float rs = 0.f;
    for(int sel=0; sel<TOPKC; ++sel){
      unsigned long long m = loc[0];
#pragma unroll
      for(int o=1;o<64;o<<=1) m = u64max(m, __shfl_xor(m,o,64));
      if(loc[0] == m){
#pragma unroll
        for(int z=0;z<TOPKC-1;++z) loc[z]=loc[z+1];
        loc[TOPKC-1]=0ull;
      }
      if(lane==0){
        float v = unmapf((unsigned)(m>>32));
        int col = (int)(0xFFFFFFFFu - (unsigned)(m & 0xFFFFFFFFu));
        knn_idx[row*TOPKC+sel] = col;
        knn_val[row*TOPKC+sel] = v;
        rs += v;
      }
    }
    if(lane==0) rowsum[row] = rs;
  }
}

// ---------------- q[i][r] = ||ent_i * W_r||^2 ----------------
__global__ __launch_bounds__(256) void k_q(const float* __restrict__ ent,
                                           const float* __restrict__ W,
                                           float* __restrict__ q){
  int wave=threadIdx.x>>6, lane=threadIdx.x&63;
  int r = blockIdx.x*4+wave;
  if(r>=N_ENT) return;
  float x = ent[(size_t)r*CH+lane];
#pragma unroll
  for(int rel=0; rel<NRELM1; rel++){
    float tt = x*W[rel*CH+lane];
    float s = waveReduceSum(tt*tt);
    if(lane==0) q[r*NRELM1+rel]=s;
  }
}

// ---------------- per-head edge aggregation (contiguous sorted arrays) ----------------
__global__ __launch_bounds__(256) void k_edge_agg(
    const int* __restrict__ trS, const int* __restrict__ startE,
    const float* __restrict__ ent, const float* __restrict__ W,
    const float* __restrict__ q, float* __restrict__ wbuf,
    float* __restrict__ agg){
  int wave=threadIdx.x>>6, lane=threadIdx.x&63;
  int h = blockIdx.x*4+wave;
  if(h>=N_ENT) return;
  int s = startE[h], e2 = startE[h+1];

  float qh[NRELM1];
#pragma unroll
  for(int r=0;r<NRELM1;r++) qh[r] = q[h*NRELM1+r];

  float mx = 0.f;
  for(int p=s+lane; p<e2; p+=64){
    int tr = trS[p];
    int tl = tr & 8191, r = tr>>13;
    float att = qh[r]*q[tl*NRELM1+r];
    wbuf[p] = att;
    mx = fmaxf(mx, att);
  }
  mx = waveReduceMax(mx);

  float dn = 0.f;
  for(int p=s+lane; p<e2; p+=64){
    float e = expf(wbuf[p]-mx);
    wbuf[p] = e;
    dn += e;
  }
  dn = waveReduceSum(dn);
  float inv = (dn>0.f) ? 1.f/dn : 0.f;

  float wr[NRELM1];
#pragma unroll
  for(int r=0;r<NRELM1;r++) wr[r] = W[r*CH+lane];
  float acc = 0.f;
  for(int p=s; p<e2; p++){
    int tr = trS[p];
    int tl = tr & 8191, r = tr>>13;
    float wgt = wbuf[p]*inv;
    acc = fmaf(wgt*wr[r], ent[(size_t)tl*CH+lane], acc);
  }
  agg[(size_t)h*CH+lane] = acc;
}

// ---------------- per-user: sparse agg + gated score + l2norm + residual ----------------
__global__ __launch_bounds__(256) void k_user(
    const int* __restrict__ icolsS, const float* __restrict__ ivalsS,
    const int* __restrict__ startU,
    const float* __restrict__ ent, const float* __restrict__ W,
    float* __restrict__ usr, float* __restrict__ usr_res){
  int wave=threadIdx.x>>6, lane=threadIdx.x&63;
  int u = blockIdx.x*4+wave;
  if(u>=N_USR) return;
  float ue = usr[(size_t)u*CH+lane];
  float l[NRELM1];
#pragma unroll
  for(int r=0;r<NRELM1;r++) l[r] = waveReduceSum(ue*W[r*CH+lane]);
  float lm = l[0];
#pragma unroll
  for(int r=1;r<NRELM1;r++) lm = fmaxf(lm,l[r]);
  float se=0.f;
#pragma unroll
  for(int r=0;r<NRELM1;r++){ l[r]=expf(l[r]-lm); se+=l[r]; }
  float inv = 1.f/se;
  float g = 0.f;
#pragma unroll
  for(int r=0;r<NRELM1;r++) g = fmaf(l[r]*inv, W[r*CH+lane], g);
  float acc=0.f;
  int s=startU[u], e2=startU[u+1];
  for(int p=s;p<e2;p++){
    acc = fmaf(ivalsS[p], ent[(size_t)icolsS[p]*CH+lane], acc);
  }
  float res = acc*(1.f+g);
  float nrm = sqrtf(waveReduceSum(res*res));
  float outv = res / fmaxf(nrm, 1e-12f);
  usr_res[(size_t)u*CH+lane] += outv;
  usr[(size_t)u*CH+lane] = outv;
}

// ---------------- entity finalize: l2norm + residual ----------------
__global__ __launch_bounds__(256) void k_entfin(const float* __restrict__ agg,
                                                float* __restrict__ cur,
                                                float* __restrict__ res){
  int wave=threadIdx.x>>6, lane=threadIdx.x&63;
  int r = blockIdx.x*4+wave;
  if(r>=N_ENT) return;
  float v = agg[(size_t)r*CH+lane];
  float nrm = sqrtf(waveReduceSum(v*v));
  float outv = v / fmaxf(nrm, 1e-12f);
  cur[(size_t)r*CH+lane]=outv;
  res[(size_t)r*CH+lane]+=outv;
}

// ---------------- fused adj writer: coalesced zeros, then direct patch ----------------
__global__ __launch_bounds__(256) void k_write_adj(
    const int* __restrict__ ki0, const float* __restrict__ kv0,
    const float* __restrict__ rs0,
    const int* __restrict__ ki1, const float* __restrict__ kv1,
    const float* __restrict__ rs1,
    float* __restrict__ adj){
  const int row = blockIdx.x;
  const int t = threadIdx.x;
  __shared__ int   cols[2*TOPKC];
  __shared__ float vals[2*TOPKC];

  if(t < TOPKC){
    int c = ki1[row*TOPKC+t];
    cols[t] = c;
    vals[t] = 0.5f * kv1[row*TOPKC+t] / (sqrtf(rs1[row]) * sqrtf(rs1[c]));
  } else if(t < 2*TOPKC){
    int i = t - TOPKC;
    int c = ki0[row*TOPKC+i];
    cols[t] = c;
    vals[t] = 0.5f * kv0[row*TOPKC+i] / (sqrtf(rs0[row]) * sqrtf(rs0[c]));
  }
  __syncthreads();
  if(t==0){
    for(int i=TOPKC;i<2*TOPKC;i++){
      int c = cols[i];
      for(int j=0;j<TOPKC;j++){
        if(cols[j]==c){ vals[j]+=vals[i]; cols[i]=-1; break; }
      }
    }
  }
  __syncthreads();

  float4* adj4 = (float4*)(adj + (size_t)row*N_ENT);
  float4 z = {0.f,0.f,0.f,0.f};
#pragma unroll
  for(int k=0;k<8;k++) adj4[k*256 + t] = z;
  __syncthreads();
  if(t < 2*TOPKC){
    int c = cols[t];
    if(c >= 0) adj[(size_t)row*N_ENT + c] = vals[t];
  }
}

extern "C" void kernel_launch(void* const* d_in, const int* in_sizes, int n_in,
                              void* d_out, int out_size, void* d_ws, size_t ws_size,
                              hipStream_t stream){
  const float* user_emb   = (const float*)d_in[0];
  const float* entity_emb = (const float*)d_in[1];
  const int*   edge_index = (const int*)d_in[2];
  const int*   edge_type  = (const int*)d_in[3];
  const int*   inter_idx  = (const int*)d_in[4];
  const float* inter_vals = (const float*)d_in[5];
  const float* W          = (const float*)d_in[6];

  const int* head  = edge_index;
  const int* tail  = edge_index + N_EDGEC;
  const int* irows = inter_idx;
  const int* icols = inter_idx + NNZC;

  float* out     = (float*)d_out;
  float* ent_res = out;
  float* usr_res = out + (size_t)N_ENT*CH;
  float* adj     = out + (size_t)N_ENT*CH + (size_t)N_USR*CH;

  char* wp = (char*)d_ws;
  auto alloc = [&](size_t bytes)->void*{
    void* p = (void*)wp; wp += (bytes+255)/256*256; return p;
  };
  ushort* abufA  = (ushort*)alloc((size_t)N_ENT*KSPLIT*2);
  ushort* abufB  = (ushort*)alloc((size_t)N_ENT*KSPLIT*2);
  float* rowmax  = (float*)alloc((size_t)N_ENT*NTILE*4);
  float* cur_ent = (float*)alloc((size_t)N_ENT*CH*4);
  float* cur_usr = (float*)alloc((size_t)N_USR*CH*4);
  float* agg     = (float*)alloc((size_t)N_ENT*CH*4);
  float* q       = (float*)alloc((size_t)N_ENT*NRELM1*4);
  int*   histE   = (int*)alloc((size_t)N_ENT*4);
  int*   startE  = (int*)alloc((size_t)(N_ENT+1)*4);
  int*   cursorE = (int*)alloc((size_t)N_ENT*4);
  int*   trS     = (int*)alloc((size_t)N_EDGEC*4);
  int*   histU   = (int*)alloc((size_t)N_USR*4);
  int*   startU  = (int*)alloc((size_t)(N_USR+1)*4);
  int*   cursorU = (int*)alloc((size_t)N_USR*4);
  int*   icolsS  = (int*)alloc((size_t)NNZC*4);
  float* ivalsS  = (float*)alloc((size_t)NNZC*4);
  int*   knn_idx0= (int*)alloc((size_t)N_ENT*TOPKC*4);
  float* knn_val0= (float*)alloc((size_t)N_ENT*TOPKC*4);
  float* rowsum0 = (float*)alloc((size_t)N_ENT*4);
  int*   knn_idx1= (int*)alloc((size_t)N_ENT*TOPKC*4);
  float* knn_val1= (float*)alloc((size_t)N_ENT*TOPKC*4);
  float* rowsum1 = (float*)alloc((size_t)N_ENT*4);

  // wbuf for edge softmax lives in the adj output region (256MB, idle during hops)
  float* wbuf = adj;

  // init
  hipMemsetAsync(histE, 0, (size_t)N_ENT*4, stream);
  hipMemsetAsync(histU, 0, (size_t)N_USR*4, stream);
  hipMemcpyAsync(ent_res, entity_emb, (size_t)N_ENT*CH*4, hipMemcpyDeviceToDevice, stream);
  hipMemcpyAsync(usr_res, user_emb,   (size_t)N_USR*CH*4, hipMemcpyDeviceToDevice, stream);
  hipMemcpyAsync(cur_ent, entity_emb, (size_t)N_ENT*CH*4, hipMemcpyDeviceToDevice, stream);
  hipMemcpyAsync(cur_usr, user_emb,   (size_t)N_USR*CH*4, hipMemcpyDeviceToDevice, stream);

  // counting sorts with fused payload gather (edges by head, inter by row)
  k_hist<<<1024,256,0,stream>>>(head, N_EDGEC, histE);
  k_hist<<<512,256,0,stream>>>(irows, NNZC, histU);
  k_scan<<<1,1024,0,stream>>>(histE, startE, cursorE, N_ENT);
  k_scan<<<1,1024,0,stream>>>(histU, startU, cursorU, N_USR);
  k_scatter_sortE<<<1024,256,0,stream>>>(head, tail, edge_type, N_EDGEC, cursorE, trS);
  k_scatter_sortU<<<512,256,0,stream>>>(irows, icols, inter_vals, NNZC, cursorU, icolsS, ivalsS);

  dim3 gg(N_ENT/128, N_ENT/128);

  // build_adj #1 on original entity_emb (sim matrix staged in the adj output region)
  k_split<<<N_ENT/4,256,0,stream>>>(entity_emb, abufA, abufB);
  k_gemm_bf16<<<gg,256,0,stream>>>(abufA, abufB, adj, rowmax);
  k_topk<<<N_ENT,64,0,stream>>>(adj, rowmax, knn_idx0, knn_val0, rowsum0);

  // 2 hops
  for(int hop=0; hop<2; ++hop){
    k_q<<<N_ENT/4,256,0,stream>>>(cur_ent, W, q);
    k_edge_agg<<<N_ENT/4,256,0,stream>>>(trS, startE, cur_ent, W, q, wbuf, agg);
    k_user<<<N_USR/4,256,0,stream>>>(icolsS, ivalsS, startU, cur_ent, W, cur_usr, usr_res);
    k_entfin<<<N_ENT/4,256,0,stream>>>(agg, cur_ent, ent_res);
  }

  // build_adj #2 on entity_res_emb
  k_split<<<N_ENT/4,256,0,stream>>>(ent_res, abufA, abufB);
  k_gemm_bf16<<<gg,256,0,stream>>>(abufA, abufB, adj, rowmax);
  k_topk<<<N_ENT,64,0,stream>>>(adj, rowmax, knn_idx1, knn_val1, rowsum1);

  // item_adj = 0.5*new + 0.5*origin, single-pass dense write (no memset, no atomics)
  k_write_adj<<<N_ENT,256,0,stream>>>(knn_idx0, knn_val0, rowsum0,
                                      knn_idx1, knn_val1, rowsum1, adj);
}

// Round 11
// 826.522 us; speedup vs baseline: 1.2906x; 1.0155x over previous
//
#include <hip/hip_runtime.h>
#include <hip/hip_bf16.h>

#define N_ENT   8192
#define N_USR   16384
#define CH      64
#define N_EDGEC 1000000
#define NNZC    500000
#define TOPKC   10
#define NRELM1  8
#define KSPLIT  384   // 6 limb-blocks of 64: A=[h,h,m,l,h,m], B=[h,m,h,h,l,m]
#define BKS     96    // K-step (4 steps of 96)
#define LDSP    104   // padded LDS row stride for main tiles
#define LDSTP   133   // padded row stride (floats) for the transpose chunk buffer
#define NTILE   64    // column tiles per row (8192/128)
#define NTRI    2080  // 64*65/2 upper-triangular tiles

typedef __bf16 bf16x8 __attribute__((ext_vector_type(8)));
typedef float  f32x4  __attribute__((ext_vector_type(4)));

static __device__ __forceinline__ float waveReduceSum(float v){
#pragma unroll
  for(int o=1;o<64;o<<=1) v += __shfl_xor(v,o,64);
  return v;
}
static __device__ __forceinline__ float waveReduceMax(float v){
#pragma unroll
  for(int o=1;o<64;o<<=1) v = fmaxf(v, __shfl_xor(v,o,64));
  return v;
}
static __device__ __forceinline__ unsigned long long u64max(unsigned long long a, unsigned long long b){
  return a>b? a: b;
}
static __device__ __forceinline__ unsigned mapf(float v){
  unsigned u = __float_as_uint(v);
  return (u & 0x80000000u) ? ~u : (u | 0x80000000u);
}
static __device__ __forceinline__ float unmapf(unsigned mk){
  unsigned uo = (mk & 0x80000000u) ? (mk ^ 0x80000000u) : ~mk;
  return __uint_as_float(uo);
}
// f32 -> bf16 RTN-even (inputs finite)
static __device__ __forceinline__ ushort f2bf(float x){
  unsigned u = __float_as_uint(x);
  return (ushort)((u + 0x7FFFu + ((u>>16)&1u)) >> 16);
}
static __device__ __forceinline__ float bf2f(ushort h){
  return __uint_as_float((unsigned)h<<16);
}

// ---------------- sorting (counting sort by segment key) ----------------
__global__ void k_hist(const int* __restrict__ keys, int n, int* __restrict__ hist){
  int i = blockIdx.x*blockDim.x + threadIdx.x;
  int stride = gridDim.x*blockDim.x;
  for(; i<n; i+=stride) atomicAdd(&hist[keys[i]], 1);
}

__global__ __launch_bounds__(1024) void k_scan(const int* __restrict__ hist,
                                               int* __restrict__ start,
                                               int* __restrict__ cursor, int n){
  __shared__ int part[1024];
  int t = threadIdx.x;
  int chunk = n/1024;
  int base = t*chunk;
  int s = 0;
  for(int i=0;i<chunk;i++) s += hist[base+i];
  part[t] = s; __syncthreads();
  for(int off=1; off<1024; off<<=1){
    int v = (t>=off) ? part[t-off] : 0;
    __syncthreads();
    part[t] += v;
    __syncthreads();
  }
  int run = (t==0) ? 0 : part[t-1];
  for(int i=0;i<chunk;i++){
    start[base+i] = run; cursor[base+i] = run;
    run += hist[base+i];
  }
  if(t==1023) start[n] = run;
}

__global__ void k_scatter_sortE(const int* __restrict__ head,
                                const int* __restrict__ tail,
                                const int* __restrict__ etype, int n,
                                int* __restrict__ cursor, int* __restrict__ trS){
  int i = blockIdx.x*blockDim.x + threadIdx.x;
  int stride = gridDim.x*blockDim.x;
  for(; i<n; i+=stride){
    int pos = atomicAdd(&cursor[head[i]], 1);
    trS[pos] = (tail[i] & 8191) | ((etype[i]-1)<<13);
  }
}

__global__ void k_scatter_sortU(const int* __restrict__ irows,
                                const int* __restrict__ icols,
                                const float* __restrict__ ivals, int n,
                                int* __restrict__ cursor,
                                int* __restrict__ icolsS, float* __restrict__ ivalsS){
  int i = blockIdx.x*blockDim.x + threadIdx.x;
  int stride = gridDim.x*blockDim.x;
  for(; i<n; i+=stride){
    int pos = atomicAdd(&cursor[irows[i]], 1);
    icolsS[pos] = icols[i];
    ivalsS[pos] = ivals[i];
  }
}

// ---------------- normalize + triple-bf16 split into A/B limb layouts ----------------
__global__ __launch_bounds__(256) void k_split(const float* __restrict__ in,
                                               ushort* __restrict__ outA,
                                               ushort* __restrict__ outB){
  int wave = threadIdx.x>>6, lane = threadIdx.x&63;
  int r = blockIdx.x*4 + wave;
  float v = in[(size_t)r*CH+lane];
  float ss = waveReduceSum(v*v);
  float x = v / sqrtf(ss);
  ushort h = f2bf(x);
  float r1 = x - bf2f(h);
  ushort m = f2bf(r1);
  float r2 = r1 - bf2f(m);
  ushort l = f2bf(r2);
  ushort* oA = outA + (size_t)r*KSPLIT;
  ushort* oB = outB + (size_t)r*KSPLIT;
  oA[lane]     =h; oA[64+lane] =h; oA[128+lane]=m;
  oA[192+lane] =l; oA[256+lane]=h; oA[320+lane]=m;
  oB[lane]     =h; oB[64+lane] =m; oB[128+lane]=h;
  oB[192+lane] =h; oB[256+lane]=l; oB[320+lane]=m;
}

// ---------------- symmetric sim GEMM (upper-triangular blocks) ----------------
// C = A~ * B~^T is exactly symmetric (limb-block sum is symmetric in i,j), so
// compute only by<=bx tiles; off-diagonal blocks also store the mirrored tile
// (via LDS transpose, coalesced) and the mirror's rowmax (= per-column max).
__global__ __launch_bounds__(256) void k_gemm_bf16(const ushort* __restrict__ A,
                                                   const ushort* __restrict__ B,
                                                   float* __restrict__ C,
                                                   float* __restrict__ rowmax){
  __shared__ __align__(16) ushort As[128*LDSP];
  __shared__ __align__(16) ushort Bs[128*LDSP];
  const int tid = threadIdx.x, lane = tid&63, wid = tid>>6;

  // decode linear block id -> (by, bx), by<=bx   S(r) = r*64 - r(r-1)/2
  int bid = blockIdx.x;
  int by = (int)((129.0f - sqrtf(16641.0f - 8.0f*(float)bid)) * 0.5f);
  while(((by+1)*64 - ((by+1)*by)/2) <= bid) by++;
  while((by*64 - (by*(by-1))/2) > bid) by--;
  int bx = by + (bid - (by*64 - (by*(by-1))/2));

  const int bi = by*128, bj = bx*128;
  const int wr = (wid>>1)*64, wc = (wid&1)*64;
  const int r16 = lane&15, kg = lane>>4;

  f32x4 acc[4][4] = {};

  const uint4* gA = (const uint4*)A + (size_t)bi*(KSPLIT/8);
  const uint4* gB = (const uint4*)B + (size_t)bj*(KSPLIT/8);
  const int row2 = tid>>1, half = tid&1;

  for(int s=0; s<KSPLIT/BKS; ++s){
    __syncthreads();
#pragma unroll
    for(int jj=0;jj<6;jj++){
      *(uint4*)&As[row2*LDSP + half*48 + jj*8] = gA[row2*(KSPLIT/8) + s*12 + half*6 + jj];
      *(uint4*)&Bs[row2*LDSP + half*48 + jj*8] = gB[row2*(KSPLIT/8) + s*12 + half*6 + jj];
    }
    __syncthreads();
#pragma unroll
    for(int kk=0;kk<3;kk++){
      bf16x8 a[4], b[4];
#pragma unroll
      for(int m=0;m<4;m++)
        a[m] = *(const bf16x8*)&As[(wr+m*16+r16)*LDSP + kk*32 + kg*8];
#pragma unroll
      for(int n=0;n<4;n++)
        b[n] = *(const bf16x8*)&Bs[(wc+n*16+r16)*LDSP + kk*32 + kg*8];
#pragma unroll
      for(int m=0;m<4;m++)
#pragma unroll
        for(int n=0;n<4;n++)
          acc[m][n] = __builtin_amdgcn_mfma_f32_16x16x32_bf16(a[m], b[n], acc[m][n], 0,0,0);
    }
  }

  // ---- direct tile store. C/D layout: col = lane&15, row = (lane>>4)*4 + reg ----
#pragma unroll
  for(int m=0;m<4;m++){
#pragma unroll
    for(int n=0;n<4;n++){
      size_t base = (size_t)(bi + wr + m*16 + kg*4)*N_ENT + (bj + wc + n*16 + r16);
      C[base]          = acc[m][n][0];
      C[base+N_ENT]    = acc[m][n][1];
      C[base+2*N_ENT]  = acc[m][n][2];
      C[base+3*N_ENT]  = acc[m][n][3];
    }
  }

  // ---- tmax: per-row max of this tile (over cols) ----
  float tmax[4][4];   // [m][reg]
#pragma unroll
  for(int m=0;m<4;m++){
#pragma unroll
    for(int rg=0;rg<4;rg++){
      float v = acc[m][0][rg];
      v = fmaxf(v, acc[m][1][rg]);
      v = fmaxf(v, acc[m][2][rg]);
      v = fmaxf(v, acc[m][3][rg]);
#pragma unroll
      for(int o=1;o<16;o<<=1) v = fmaxf(v, __shfl_xor(v, o, 64));
      tmax[m][rg] = v;
    }
  }
  // ---- cm: per-column max of this tile (over rows), for the mirror tile ----
  float cm[4];        // [n]
#pragma unroll
  for(int n=0;n<4;n++){
    float v = acc[0][n][0];
#pragma unroll
    for(int m=0;m<4;m++)
#pragma unroll
      for(int rg=0;rg<4;rg++) v = fmaxf(v, acc[m][n][rg]);
    v = fmaxf(v, __shfl_xor(v, 16, 64));
    v = fmaxf(v, __shfl_xor(v, 32, 64));
    cm[n] = v;
  }

  __syncthreads();                  // main-loop LDS reads done everywhere
  float* rm  = (float*)Bs;          // 128 floats: row maxes (combine wc halves)
  float* cmb = ((float*)Bs) + 128;  // 128 floats: col maxes (combine wr halves)
  if(((wid&1)==0) && r16==0){
#pragma unroll
    for(int m=0;m<4;m++)
#pragma unroll
      for(int rg=0;rg<4;rg++)
        rm[wr + m*16 + kg*4 + rg] = tmax[m][rg];
  }
  if(wid<2 && kg==0){               // wr==0 waves hold cols wc..wc+63
#pragma unroll
    for(int n=0;n<4;n++) cmb[wc + n*16 + r16] = cm[n];
  }
  __syncthreads();
  if(((wid&1)==1) && r16==0){       // direct rowmax: rows bi.., tile bx
#pragma unroll
    for(int m=0;m<4;m++)
#pragma unroll
      for(int rg=0;rg<4;rg++){
        int rrow = wr + m*16 + kg*4 + rg;
        rowmax[(size_t)(bi+rrow)*NTILE + bx] = fmaxf(tmax[m][rg], rm[rrow]);
      }
  }
  if(by != bx && wid>=2 && kg==0){  // mirror rowmax: rows bj.., tile by
#pragma unroll
    for(int n=0;n<4;n++){
      int ccol = wc + n*16 + r16;
      rowmax[(size_t)(bj+ccol)*NTILE + by] = fmaxf(cm[n], cmb[ccol]);
    }
  }

  // ---- mirror tile store via chunked LDS transpose (coalesced 128B rows) ----
  if(by != bx){
    float* ldsT = (float*)As;       // 32 x LDSTP floats = 17 KB (fits in As)
    for(int q=0;q<4;q++){
      __syncthreads();
      // write phase: each (wave, n) pair belongs to chunk (wc>>5)+(n>>1)
#pragma unroll
      for(int n=0;n<4;n++){
        if(((wc>>5) + (n>>1)) == q){
          int cl = ((n&1)*16) + r16;      // local col in chunk, 0..31
#pragma unroll
          for(int m=0;m<4;m++)
#pragma unroll
            for(int rg=0;rg<4;rg++)
              ldsT[cl*LDSTP + wr + m*16 + kg*4 + rg] = acc[m][n][rg];
        }
      }
      __syncthreads();
      // read+store: row (bj + q*32 + cr), cols bi..bi+127, float4 coalesced
      int cr = tid>>3;                    // 0..31
      int g  = tid&7;                     // 0..7
      float* crow = C + (size_t)(bj + q*32 + cr)*N_ENT + bi;
#pragma unroll
      for(int f=0; f<4; ++f){
        int cidx = (g + f*8)*4;           // 0,32,..124 dwords
        float4 v = *(float4*)&ldsT[cr*LDSTP + cidx];
        *(float4*)&crow[cidx] = v;
      }
    }
  }
}

// ---------------- per-row top-k via tile-max pruning, one wave per row ----------------
#define CANDCAP 256
__global__ __launch_bounds__(64) void k_topk(const float* __restrict__ S,
                                             const float* __restrict__ rowmax,
                                             int* __restrict__ knn_idx,
                                             float* __restrict__ knn_val,
                                             float* __restrict__ rowsum){
  const int row = blockIdx.x;
  const int lane = threadIdx.x;
  const float4* s4 = (const float4*)(S + (size_t)row*N_ENT);

  __shared__ unsigned long long cand[CANDCAP];
  __shared__ int tlist[NTILE];
  __shared__ int cnt, tcnt;
  if(lane==0){ cnt=0; tcnt=0; }
  __syncthreads();

  // exact 10th-largest tile max (lane id breaks ties -> unique removal)
  float tm = rowmax[(size_t)row*NTILE + lane];
  unsigned long long work = ((unsigned long long)mapf(tm)<<32) | (unsigned)lane;
  unsigned long long w = 0;
  for(int sel=0; sel<TOPKC; ++sel){
    w = work;
#pragma unroll
    for(int o=1;o<64;o<<=1) w = u64max(w, __shfl_xor(w,o,64));
    if(work == w) work = 0ull;
  }
  float tauf = unmapf((unsigned)(w>>32));

  if(tm >= tauf){ int p = atomicAdd(&tcnt,1); tlist[p] = lane; }
  __syncthreads();
  int nt = tcnt;

  // scan qualifying tiles, 2 tiles per iteration (32 lanes each)
  for(int i = (lane>>5); i < nt; i += 2){
    int t  = tlist[i];
    int fo = lane&31;
    float4 v = s4[t*32 + fo];
    int c0 = t*128 + fo*4;
    float vv[4] = {v.x,v.y,v.z,v.w};
#pragma unroll
    for(int j=0;j<4;j++){
      if(vv[j] >= tauf){
        int pos = atomicAdd(&cnt,1);
        if(pos < CANDCAP)
          cand[pos] = ((unsigned long long)mapf(vv[j])<<32)
                    | (unsigned long long)(0xFFFFFFFFu - (unsigned)(c0+j));
      }
    }
  }
  __syncthreads();
  int n = cnt;

  if(n <= CANDCAP){
    unsigned long long c0 = (lane      < n) ? cand[lane]       : 0ull;
    unsigned long long c1 = (lane+64   < n) ? cand[lane+64]    : 0ull;
    unsigned long long c2 = (lane+128  < n) ? cand[lane+128]   : 0ull;
    unsigned long long c3 = (lane+192  < n) ? cand[lane+192]   : 0ull;
    float rs = 0.f;
    for(int sel=0; sel<TOPKC; ++sel){
      unsigned long long m = u64max(u64max(c0,c1), u64max(c2,c3));
#pragma unroll
      for(int o=1;o<64;o<<=1) m = u64max(m, __shfl_xor(m,o,64));
      if(c0==m) c0=0ull; else if(c1==m) c1=0ull;
      else if(c2==m) c2=0ull; else if(c3==m) c3=0ull;
      if(lane==0){
        float v = unmapf((unsigned)(m>>32));
        int col = (int)(0xFFFFFFFFu - (unsigned)(m & 0xFFFFFFFFu));
        knn_idx[row*TOPKC+sel] = col;
        knn_val[row*TOPKC+sel] = v;
        rs += v;
      }
    }
    if(lane==0) rowsum[row] = rs;
  } else {
    // pathological fallback: exact register insertion scan over the full row
    unsigned long long loc[TOPKC];
#pragma unroll
    for(int i=0;i<TOPKC;i++) loc[i]=0ull;
    for(int it=0; it<N_ENT/256; ++it){
      int vi = it*64+lane;
      float4 v = s4[vi];
      int c0i = vi*4;
      float vv[4] = {v.x,v.y,v.z,v.w};
#pragma unroll
      for(int j=0;j<4;j++){
        unsigned u = mapf(vv[j]);
        unsigned long long key = ((unsigned long long)u<<32)
                               | (unsigned long long)(0xFFFFFFFFu - (unsigned)(c0i+j));
        if(key > loc[TOPKC-1]){
          unsigned long long t = key;
#pragma unroll
          for(int z=0; z<TOPKC; ++z){
            if(t > loc[z]){ unsigned long long tmp=loc[z]; loc[z]=t; t=tmp; }
          }
        }
      }
    }
    float rs = 0.f;
    for(int sel=0; sel<TOPKC; ++sel){
      unsigned long long m = loc[0];
#pragma unroll
      for(int o=1;o<64;o<<=1) m = u64max(m, __shfl_xor(m,o,64));
      if(loc[0] == m){
#pragma unroll
        for(int z=0;z<TOPKC-1;++z) loc[z]=loc[z+1];
        loc[TOPKC-1]=0ull;
      }
      if(lane==0){
        float v = unmapf((unsigned)(m>>32));
        int col = (int)(0xFFFFFFFFu - (unsigned)(m & 0xFFFFFFFFu));
        knn_idx[row*TOPKC+sel] = col;
        knn_val[row*TOPKC+sel] = v;
        rs += v;
      }
    }
    if(lane==0) rowsum[row] = rs;
  }
}

// ---------------- q[i][r] = ||ent_i * W_r||^2 ----------------
__global__ __launch_bounds__(256) void k_q(const float* __restrict__ ent,
                                           const float* __restrict__ W,
                                           float* __restrict__ q){
  int wave=threadIdx.x>>6, lane=threadIdx.x&63;
  int r = blockIdx.x*4+wave;
  if(r>=N_ENT) return;
  float x = ent[(size_t)r*CH+lane];
#pragma unroll
  for(int rel=0; rel<NRELM1; rel++){
    float tt = x*W[rel*CH+lane];
    float s = waveReduceSum(tt*tt);
    if(lane==0) q[r*NRELM1+rel]=s;
  }
}

// ---------------- per-head edge aggregation (contiguous sorted arrays) ----------------
__global__ __launch_bounds__(256) void k_edge_agg(
    const int* __restrict__ trS, const int* __restrict__ startE,
    const float* __restrict__ ent, const float* __restrict__ W,
    const float* __restrict__ q, float* __restrict__ wbuf,
    float* __restrict__ agg){
  int wave=threadIdx.x>>6, lane=threadIdx.x&63;
  int h = blockIdx.x*4+wave;
  if(h>=N_ENT) return;
  int s = startE[h], e2 = startE[h+1];

  float qh[NRELM1];
#pragma unroll
  for(int r=0;r<NRELM1;r++) qh[r] = q[h*NRELM1+r];

  float mx = 0.f;
  for(int p=s+lane; p<e2; p+=64){
    int tr = trS[p];
    int tl = tr & 8191, r = tr>>13;
    float att = qh[r]*q[tl*NRELM1+r];
    wbuf[p] = att;
    mx = fmaxf(mx, att);
  }
  mx = waveReduceMax(mx);

  float dn = 0.f;
  for(int p=s+lane; p<e2; p+=64){
    float e = expf(wbuf[p]-mx);
    wbuf[p] = e;
    dn += e;
  }
  dn = waveReduceSum(dn);
  float inv = (dn>0.f) ? 1.f/dn : 0.f;

  float wr[NRELM1];
#pragma unroll
  for(int r=0;r<NRELM1;r++) wr[r] = W[r*CH+lane];
  float acc = 0.f;
  for(int p=s; p<e2; p++){
    int tr = trS[p];
    int tl = tr & 8191, r = tr>>13;
    float wgt = wbuf[p]*inv;
    acc = fmaf(wgt*wr[r], ent[(size_t)tl*CH+lane], acc);
  }
  agg[(size_t)h*CH+lane] = acc;
}

// ---------------- per-user: sparse agg + gated score + l2norm + residual ----------------
__global__ __launch_bounds__(256) void k_user(
    const int* __restrict__ icolsS, const float* __restrict__ ivalsS,
    const int* __restrict__ startU,
    const float* __restrict__ ent, const float* __restrict__ W,
    float* __restrict__ usr, float* __restrict__ usr_res){
  int wave=threadIdx.x>>6, lane=threadIdx.x&63;
  int u = blockIdx.x*4+wave;
  if(u>=N_USR) return;
  float ue = usr[(size_t)u*CH+lane];
  float l[NRELM1];
#pragma unroll
  for(int r=0;r<NRELM1;r++) l[r] = waveReduceSum(ue*W[r*CH+lane]);
  float lm = l[0];
#pragma unroll
  for(int r=1;r<NRELM1;r++) lm = fmaxf(lm,l[r]);
  float se=0.f;
#pragma unroll
  for(int r=0;r<NRELM1;r++){ l[r]=expf(l[r]-lm); se+=l[r]; }
  float inv = 1.f/se;
  float g = 0.f;
#pragma unroll
  for(int r=0;r<NRELM1;r++) g = fmaf(l[r]*inv, W[r*CH+lane], g);
  float acc=0.f;
  int s=startU[u], e2=startU[u+1];
  for(int p=s;p<e2;p++){
    acc = fmaf(ivalsS[p], ent[(size_t)icolsS[p]*CH+lane], acc);
  }
  float res = acc*(1.f+g);
  float nrm = sqrtf(waveReduceSum(res*res));
  float outv = res / fmaxf(nrm, 1e-12f);
  usr_res[(size_t)u*CH+lane] += outv;
  usr[(size_t)u*CH+lane] = outv;
}

// ---------------- entity finalize: l2norm + residual ----------------
__global__ __launch_bounds__(256) void k_entfin(const float* __restrict__ agg,
                                                float* __restrict__ cur,
                                                float* __restrict__ res){
  int wave=threadIdx.x>>6, lane=threadIdx.x&63;
  int r = blockIdx.x*4+wave;
  if(r>=N_ENT) return;
  float v = agg[(size_t)r*CH+lane];
  float nrm = sqrtf(waveReduceSum(v*v));
  float outv = v / fmaxf(nrm, 1e-12f);
  cur[(size_t)r*CH+lane]=outv;
  res[(size_t)r*CH+lane]+=outv;
}

// ---------------- fused adj writer: coalesced zeros, then direct patch ----------------
__global__ __launch_bounds__(256) void k_write_adj(
    const int* __restrict__ ki0, const float* __restrict__ kv0,
    const float* __restrict__ rs0,
    const int* __restrict__ ki1, const float* __restrict__ kv1,
    const float* __restrict__ rs1,
    float* __restrict__ adj){
  const int row = blockIdx.x;
  const int t = threadIdx.x;
  __shared__ int   cols[2*TOPKC];
  __shared__ float vals[2*TOPKC];

  if(t < TOPKC){
    int c = ki1[row*TOPKC+t];
    cols[t] = c;
    vals[t] = 0.5f * kv1[row*TOPKC+t] / (sqrtf(rs1[row]) * sqrtf(rs1[c]));
  } else if(t < 2*TOPKC){
    int i = t - TOPKC;
    int c = ki0[row*TOPKC+i];
    cols[t] = c;
    vals[t] = 0.5f * kv0[row*TOPKC+i] / (sqrtf(rs0[row]) * sqrtf(rs0[c]));
  }
  __syncthreads();
  if(t==0){
    for(int i=TOPKC;i<2*TOPKC;i++){
      int c = cols[i];
      for(int j=0;j<TOPKC;j++){
        if(cols[j]==c){ vals[j]+=vals[i]; cols[i]=-1; break; }
      }
    }
  }
  __syncthreads();

  float4* adj4 = (float4*)(adj + (size_t)row*N_ENT);
  float4 z = {0.f,0.f,0.f,0.f};
#pragma unroll
  for(int k=0;k<8;k++) adj4[k*256 + t] = z;
  __syncthreads();
  if(t < 2*TOPKC){
    int c = cols[t];
    if(c >= 0) adj[(size_t)row*N_ENT + c] = vals[t];
  }
}

extern "C" void kernel_launch(void* const* d_in, const int* in_sizes, int n_in,
                              void* d_out, int out_size, void* d_ws, size_t ws_size,
                              hipStream_t stream){
  const float* user_emb   = (const float*)d_in[0];
  const float* entity_emb = (const float*)d_in[1];
  const int*   edge_index = (const int*)d_in[2];
  const int*   edge_type  = (const int*)d_in[3];
  const int*   inter_idx  = (const int*)d_in[4];
  const float* inter_vals = (const float*)d_in[5];
  const float* W          = (const float*)d_in[6];

  const int* head  = edge_index;
  const int* tail  = edge_index + N_EDGEC;
  const int* irows = inter_idx;
  const int* icols = inter_idx + NNZC;

  float* out     = (float*)d_out;
  float* ent_res = out;
  float* usr_res = out + (size_t)N_ENT*CH;
  float* adj     = out + (size_t)N_ENT*CH + (size_t)N_USR*CH;

  char* wp = (char*)d_ws;
  auto alloc = [&](size_t bytes)->void*{
    void* p = (void*)wp; wp += (bytes+255)/256*256; return p;
  };
  ushort* abufA  = (ushort*)alloc((size_t)N_ENT*KSPLIT*2);
  ushort* abufB  = (ushort*)alloc((size_t)N_ENT*KSPLIT*2);
  float* rowmax  = (float*)alloc((size_t)N_ENT*NTILE*4);
  float* cur_ent = (float*)alloc((size_t)N_ENT*CH*4);
  float* cur_usr = (float*)alloc((size_t)N_USR*CH*4);
  float* agg     = (float*)alloc((size_t)N_ENT*CH*4);
  float* q       = (float*)alloc((size_t)N_ENT*NRELM1*4);
  int*   histE   = (int*)alloc((size_t)N_ENT*4);
  int*   startE  = (int*)alloc((size_t)(N_ENT+1)*4);
  int*   cursorE = (int*)alloc((size_t)N_ENT*4);
  int*   trS     = (int*)alloc((size_t)N_EDGEC*4);
  int*   histU   = (int*)alloc((size_t)N_USR*4);
  int*   startU  = (int*)alloc((size_t)(N_USR+1)*4);
  int*   cursorU = (int*)alloc((size_t)N_USR*4);
  int*   icolsS  = (int*)alloc((size_t)NNZC*4);
  float* ivalsS  = (float*)alloc((size_t)NNZC*4);
  int*   knn_idx0= (int*)alloc((size_t)N_ENT*TOPKC*4);
  float* knn_val0= (float*)alloc((size_t)N_ENT*TOPKC*4);
  float* rowsum0 = (float*)alloc((size_t)N_ENT*4);
  int*   knn_idx1= (int*)alloc((size_t)N_ENT*TOPKC*4);
  float* knn_val1= (float*)alloc((size_t)N_ENT*TOPKC*4);
  float* rowsum1 = (float*)alloc((size_t)N_ENT*4);

  // wbuf for edge softmax lives in the adj output region (256MB, idle during hops)
  float* wbuf = adj;

  // init
  hipMemsetAsync(histE, 0, (size_t)N_ENT*4, stream);
  hipMemsetAsync(histU, 0, (size_t)N_USR*4, stream);
  hipMemcpyAsync(ent_res, entity_emb, (size_t)N_ENT*CH*4, hipMemcpyDeviceToDevice, stream);
  hipMemcpyAsync(usr_res, user_emb,   (size_t)N_USR*CH*4, hipMemcpyDeviceToDevice, stream);
  hipMemcpyAsync(cur_ent, entity_emb, (size_t)N_ENT*CH*4, hipMemcpyDeviceToDevice, stream);
  hipMemcpyAsync(cur_usr, user_emb,   (size_t)N_USR*CH*4, hipMemcpyDeviceToDevice, stream);

  // counting sorts with fused payload gather (edges by head, inter by row)
  k_hist<<<1024,256,0,stream>>>(head, N_EDGEC, histE);
  k_hist<<<512,256,0,stream>>>(irows, NNZC, histU);
  k_scan<<<1,1024,0,stream>>>(histE, startE, cursorE, N_ENT);
  k_scan<<<1,1024,0,stream>>>(histU, startU, cursorU, N_USR);
  k_scatter_sortE<<<1024,256,0,stream>>>(head, tail, edge_type, N_EDGEC, cursorE, trS);
  k_scatter_sortU<<<512,256,0,stream>>>(irows, icols, inter_vals, NNZC, cursorU, icolsS, ivalsS);

  // build_adj #1 on original entity_emb (sim matrix staged in the adj output region)
  k_split<<<N_ENT/4,256,0,stream>>>(entity_emb, abufA, abufB);
  k_gemm_bf16<<<NTRI,256,0,stream>>>(abufA, abufB, adj, rowmax);
  k_topk<<<N_ENT,64,0,stream>>>(adj, rowmax, knn_idx0, knn_val0, rowsum0);

  // 2 hops
  for(int hop=0; hop<2; ++hop){
    k_q<<<N_ENT/4,256,0,stream>>>(cur_ent, W, q);
    k_edge_agg<<<N_ENT/4,256,0,stream>>>(trS, startE, cur_ent, W, q, wbuf, agg);
    k_user<<<N_USR/4,256,0,stream>>>(icolsS, ivalsS, startU, cur_ent, W, cur_usr, usr_res);
    k_entfin<<<N_ENT/4,256,0,stream>>>(agg, cur_ent, ent_res);
  }

  // build_adj #2 on entity_res_emb
  k_split<<<N_ENT/4,256,0,stream>>>(ent_res, abufA, abufB);
  k_gemm_bf16<<<NTRI,256,0,stream>>>(abufA, abufB, adj, rowmax);
  k_topk<<<N_ENT,64,0,stream>>>(adj, rowmax, knn_idx1, knn_val1, rowsum1);

  // item_adj = 0.5*new + 0.5*origin, single-pass dense write (no memset, no atomics)
  k_write_adj<<<N_ENT,256,0,stream>>>(knn_idx0, knn_val0, rowsum0,
                                      knn_idx1, knn_val1, rowsum1, adj);
}